// Round 1
// baseline (1248.927 us; speedup 1.0000x reference)
//
#include <hip/hip_runtime.h>
#include <hip/hip_bf16.h>
#include <stdint.h>

#define TPB 256
#define EPSF 1e-5f

using bf16x8  = __attribute__((ext_vector_type(8))) __bf16;
using floatx4 = __attribute__((ext_vector_type(4))) float;

// ---------------- helpers ----------------

__device__ __forceinline__ void gload16(const void* g, void* l) {
    // async global->LDS, 16B per lane; LDS dest is wave-uniform base + lane*16
    __builtin_amdgcn_global_load_lds(
        (__attribute__((address_space(1))) void*)g,
        (__attribute__((address_space(3))) void*)l,
        16, 0, 0);
}

__device__ __forceinline__ float wave_reduce_sum(float v) {
#pragma unroll
    for (int off = 32; off > 0; off >>= 1) v += __shfl_down(v, off, 64);
    return v;
}

__device__ __forceinline__ float wave_reduce_max(float v) {
#pragma unroll
    for (int off = 32; off > 0; off >>= 1) v = fmaxf(v, __shfl_down(v, off, 64));
    return v;
}

__device__ __forceinline__ unsigned short bfbits(float f) {
    __hip_bfloat16 h = __float2bfloat16(f);  // RNE; exact for small ints
    union { __hip_bfloat16 h; unsigned short u; } cv;
    cv.h = h;
    return cv.u;
}

// ---------------- scale reduction (deterministic two-pass) ----------------

__global__ void abssum_partial(const float* __restrict__ w, int n4,
                               float* __restrict__ part) {
    const float4* w4 = (const float4*)w;
    float acc = 0.f;
    for (int i = blockIdx.x * TPB + threadIdx.x; i < n4; i += gridDim.x * TPB) {
        float4 v = w4[i];
        acc += fabsf(v.x) + fabsf(v.y) + fabsf(v.z) + fabsf(v.w);
    }
    acc = wave_reduce_sum(acc);
    __shared__ float sh[4];
    if ((threadIdx.x & 63) == 0) sh[threadIdx.x >> 6] = acc;
    __syncthreads();
    if (threadIdx.x == 0) part[blockIdx.x] = sh[0] + sh[1] + sh[2] + sh[3];
}

__global__ void finalize_scales(const float* __restrict__ part1,
                                const float* __restrict__ part2,
                                float* __restrict__ scales, int nparts, float inv_n) {
    float a = 0.f, b = 0.f;
    for (int i = threadIdx.x; i < nparts; i += TPB) { a += part1[i]; b += part2[i]; }
    a = wave_reduce_sum(a);
    b = wave_reduce_sum(b);
    __shared__ float sa[4], sb[4];
    if ((threadIdx.x & 63) == 0) { sa[threadIdx.x >> 6] = a; sb[threadIdx.x >> 6] = b; }
    __syncthreads();
    if (threadIdx.x == 0) {
        float s1 = fmaxf((sa[0] + sa[1] + sa[2] + sa[3]) * inv_n, EPSF);
        float s2 = fmaxf((sb[0] + sb[1] + sb[2] + sb[3]) * inv_n, EPSF);
        scales[0] = s1;
        scales[1] = s2;
    }
}

// ---------------- weight ternarization: store {-1,0,1} as bf16 ----------------

__global__ void quant_w_kernel(const float* __restrict__ w,
                               __hip_bfloat16* __restrict__ wq,
                               const float* __restrict__ scales, int sidx, int n4) {
    const float inv = 1.0f / scales[sidx];
    const float4* w4 = (const float4*)w;
    unsigned short* oq = (unsigned short*)wq;
    for (int i = blockIdx.x * TPB + threadIdx.x; i < n4; i += gridDim.x * TPB) {
        float4 v = w4[i];
        union { unsigned short u[4]; uint2 o; } t;
        t.u[0] = bfbits(fminf(fmaxf(rintf(v.x * inv), -1.f), 1.f));
        t.u[1] = bfbits(fminf(fmaxf(rintf(v.y * inv), -1.f), 1.f));
        t.u[2] = bfbits(fminf(fmaxf(rintf(v.z * inv), -1.f), 1.f));
        t.u[3] = bfbits(fminf(fmaxf(rintf(v.w * inv), -1.f), 1.f));
        *(uint2*)(oq + (long long)i * 4) = t.o;
    }
}

// ---------------- per-row activation quant: store int value as bf16 + row dq ----------------

template <int N4PT>  // float4s per thread; cols == N4PT * TPB * 4
__global__ void quant_rows(const float* __restrict__ in,
                           __hip_bfloat16* __restrict__ outq,
                           float* __restrict__ dq, int cols) {
    const long long row = blockIdx.x;
    const float4* r4 = (const float4*)(in + row * (long long)cols);
    float4 v[N4PT];
    float mx = 0.f;
#pragma unroll
    for (int j = 0; j < N4PT; ++j) {
        v[j] = r4[threadIdx.x + TPB * j];
        mx = fmaxf(mx, fmaxf(fmaxf(fabsf(v[j].x), fabsf(v[j].y)),
                             fmaxf(fabsf(v[j].z), fabsf(v[j].w))));
    }
    mx = wave_reduce_max(mx);
    __shared__ float sh[4];
    __shared__ float res;
    if ((threadIdx.x & 63) == 0) sh[threadIdx.x >> 6] = mx;
    __syncthreads();
    if (threadIdx.x == 0) res = fmaxf(fmaxf(sh[0], sh[1]), fmaxf(sh[2], sh[3]));
    __syncthreads();
    const float clipped = fmaxf(res, EPSF);
    const float scale = 127.f / clipped;
    if (threadIdx.x == 0) dq[row] = clipped / 127.f;
    unsigned short* oq = (unsigned short*)(outq + row * (long long)cols);
#pragma unroll
    for (int j = 0; j < N4PT; ++j) {
        const int i = threadIdx.x + TPB * j;
        union { unsigned short u[4]; uint2 w; } o;
        o.u[0] = bfbits(fminf(fmaxf(rintf(v[j].x * scale), -128.f), 127.f));
        o.u[1] = bfbits(fminf(fmaxf(rintf(v[j].y * scale), -128.f), 127.f));
        o.u[2] = bfbits(fminf(fmaxf(rintf(v[j].z * scale), -128.f), 127.f));
        o.u[3] = bfbits(fminf(fmaxf(rintf(v[j].w * scale), -128.f), 127.f));
        *(uint2*)(oq + (long long)i * 4) = o.w;
    }
}

// ---------------- GEMM: C[m,n] = (sum_k A[m,k]*B[n,k]) * dq[m] * s, optional GELU ----------------
// A: [Mtile x K] bf16 (integer values), B: [N x K] bf16 (ternary), both K-contiguous.
// m97 structure: 128x128 tile, BK=64, 4 waves x 4x4 16x16x32 fragments, global_load_lds(16B).

template <int GELU>
__global__ __launch_bounds__(256) void gemm_bt(
    const __hip_bfloat16* __restrict__ A, const __hip_bfloat16* __restrict__ B,
    float* __restrict__ C, int N, int K,
    const float* __restrict__ dq, const float* __restrict__ scales, int sidx) {
    __shared__ char la[128 * 64 * 2];
    __shared__ char lb[128 * 64 * 2];

    const int tid = threadIdx.x;
    const int lane = tid & 63;
    const int wr = (tid >> 6) >> 1;  // wave row (0..1), owns 64 rows
    const int wc = (tid >> 6) & 1;   // wave col (0..1), owns 64 cols

    const long long am0 = (long long)blockIdx.y * 128;
    const long long bn0 = (long long)blockIdx.x * 128;
    const char* Ab = (const char*)A + am0 * K * 2;
    const char* Bb = (const char*)B + bn0 * K * 2;
    const long long rb = (long long)K * 2;  // row bytes

    floatx4 acc[4][4] = {};

    const int r_st = (tid * 16) >> 7;   // staging row within 32-row chunk
    const int c_st = (tid * 16) & 127;  // staging byte col

    for (int kt = 0; kt < K; kt += 64) {
        __syncthreads();
#pragma unroll
        for (int j = 0; j < 4; ++j) {
            const int row = j * 32 + r_st;
            const long long goff = (long long)row * rb + (long long)kt * 2 + c_st;
            gload16(Ab + goff, la + j * 4096 + tid * 16);
            gload16(Bb + goff, lb + j * 4096 + tid * 16);
        }
        __syncthreads();
#pragma unroll
        for (int ks = 0; ks < 2; ++ks) {
            bf16x8 af[4], bfr[4];
            const int kb = ks * 64 + ((lane >> 4) * 16);  // byte offset in 128B row
#pragma unroll
            for (int mi = 0; mi < 4; ++mi)
                af[mi] = *(const bf16x8*)(la + (wr * 64 + mi * 16 + (lane & 15)) * 128 + kb);
#pragma unroll
            for (int ni = 0; ni < 4; ++ni)
                bfr[ni] = *(const bf16x8*)(lb + (wc * 64 + ni * 16 + (lane & 15)) * 128 + kb);
#pragma unroll
            for (int mi = 0; mi < 4; ++mi)
#pragma unroll
                for (int ni = 0; ni < 4; ++ni)
                    acc[mi][ni] = __builtin_amdgcn_mfma_f32_16x16x32_bf16(
                        af[mi], bfr[ni], acc[mi][ni], 0, 0, 0);
        }
    }

    // epilogue: C/D layout col=lane&15, row=(lane>>4)*4+reg  [m89/m91 verified]
    const float s = scales[sidx];
    const int cl = lane & 15;
    const int r0 = (lane >> 4) * 4;
#pragma unroll
    for (int mi = 0; mi < 4; ++mi) {
#pragma unroll
        for (int r = 0; r < 4; ++r) {
            const long long m = am0 + wr * 64 + mi * 16 + r0 + r;
            const float f = dq[m] * s;
#pragma unroll
            for (int ni = 0; ni < 4; ++ni) {
                const long long n = bn0 + wc * 64 + ni * 16 + cl;
                float v = acc[mi][ni][r] * f;
                if (GELU) v = 0.5f * v * (1.0f + erff(v * 0.70710678118654752440f));
                C[m * (long long)N + n] = v;
            }
        }
    }
}

// ---------------- launcher ----------------

extern "C" void kernel_launch(void* const* d_in, const int* in_sizes, int n_in,
                              void* d_out, int out_size, void* d_ws, size_t ws_size,
                              hipStream_t stream) {
    (void)n_in; (void)out_size;
    const float* x  = (const float*)d_in[0];
    const float* w1 = (const float*)d_in[1];
    const float* w2 = (const float*)d_in[2];
    float* out = (float*)d_out;

    const int D = 2048, H = 8192;
    const long long M = (long long)in_sizes[0] / D;  // 8192 tokens
    const long long GROUP = 2048;                    // rows per h-chunk
    const int nG = (int)(M / GROUP);

    // workspace carve-up (256B aligned)
    char* base = (char*)d_ws;
    size_t off = 0;
    auto alloc = [&](size_t bytes) -> char* {
        char* r = base + off;
        off = (off + bytes + 255) & ~(size_t)255;
        return r;
    };

    // full-hq plan needs ~288MB; chunked-hq plan needs ~192MB
    const bool fullH = ws_size >= (size_t)310 * 1024 * 1024;

    float* part1 = (float*)alloc(2048 * 4);
    float* part2 = (float*)alloc(2048 * 4);
    float* scales = (float*)alloc(256);
    float* dqx = (float*)alloc((size_t)M * 4);
    float* dqh = (float*)alloc((size_t)M * 4);  // sized for full M (tiny)
    __hip_bfloat16* w1q = (__hip_bfloat16*)alloc((size_t)H * D * 2);
    __hip_bfloat16* w2q = (__hip_bfloat16*)alloc((size_t)H * D * 2);
    __hip_bfloat16* xq  = (__hip_bfloat16*)alloc((size_t)M * D * 2);
    __hip_bfloat16* hq  = (__hip_bfloat16*)alloc((size_t)(fullH ? M : GROUP) * H * 2);
    float* hch = (float*)alloc((size_t)GROUP * H * 4);

    const int nw4 = H * D / 4;  // 4,194,304 float4s per weight
    abssum_partial<<<2048, TPB, 0, stream>>>(w1, nw4, part1);
    abssum_partial<<<2048, TPB, 0, stream>>>(w2, nw4, part2);
    finalize_scales<<<1, TPB, 0, stream>>>(part1, part2, scales, 2048,
                                           1.0f / (float)(H * D));
    quant_w_kernel<<<2048, TPB, 0, stream>>>(w1, w1q, scales, 0, nw4);
    quant_w_kernel<<<2048, TPB, 0, stream>>>(w2, w2q, scales, 1, nw4);
    quant_rows<2><<<(int)M, TPB, 0, stream>>>(x, xq, dqx, D);  // D=2048 -> 2 float4/thread

    if (fullH) {
        for (int g = 0; g < nG; ++g) {
            const long long m0 = g * GROUP;
            gemm_bt<1><<<dim3(H / 128, (int)(GROUP / 128)), TPB, 0, stream>>>(
                xq + m0 * D, w1q, hch, H, D, dqx + m0, scales, 0);
            quant_rows<8><<<(int)GROUP, TPB, 0, stream>>>(hch, hq + m0 * H, dqh + m0, H);
        }
        gemm_bt<0><<<dim3(D / 128, (int)(M / 128)), TPB, 0, stream>>>(
            hq, w2q, out, D, H, dqh, scales, 1);
    } else {
        for (int g = 0; g < nG; ++g) {
            const long long m0 = g * GROUP;
            gemm_bt<1><<<dim3(H / 128, (int)(GROUP / 128)), TPB, 0, stream>>>(
                xq + m0 * D, w1q, hch, H, D, dqx + m0, scales, 0);
            quant_rows<8><<<(int)GROUP, TPB, 0, stream>>>(hch, hq, dqh, H);
            gemm_bt<0><<<dim3(D / 128, (int)(GROUP / 128)), TPB, 0, stream>>>(
                hq, w2q, out + m0 * D, D, H, dqh, scales, 1);
        }
    }
}

// Round 2
// 1174.554 us; speedup vs baseline: 1.0633x; 1.0633x over previous
//
#include <hip/hip_runtime.h>
#include <hip/hip_bf16.h>
#include <stdint.h>

#define TPB 256
#define EPSF 1e-5f

using bf16x8  = __attribute__((ext_vector_type(8))) __bf16;
using floatx4 = __attribute__((ext_vector_type(4))) float;

// ---------------- helpers ----------------

__device__ __forceinline__ void gload16(const void* g, void* l) {
    __builtin_amdgcn_global_load_lds(
        (__attribute__((address_space(1))) void*)g,
        (__attribute__((address_space(3))) void*)l,
        16, 0, 0);
}

__device__ __forceinline__ float wave_reduce_sum(float v) {
#pragma unroll
    for (int off = 32; off > 0; off >>= 1) v += __shfl_down(v, off, 64);
    return v;
}

__device__ __forceinline__ float wave_reduce_max(float v) {
#pragma unroll
    for (int off = 32; off > 0; off >>= 1) v = fmaxf(v, __shfl_down(v, off, 64));
    return v;
}

__device__ __forceinline__ unsigned short bfbits(float f) {
    __hip_bfloat16 h = __float2bfloat16(f);
    union { __hip_bfloat16 h; unsigned short u; } cv;
    cv.h = h;
    return cv.u;
}

// ---------------- scale reduction (deterministic two-pass) ----------------

__global__ void abssum_partial(const float* __restrict__ w, int n4,
                               float* __restrict__ part) {
    const float4* w4 = (const float4*)w;
    float acc = 0.f;
    for (int i = blockIdx.x * TPB + threadIdx.x; i < n4; i += gridDim.x * TPB) {
        float4 v = w4[i];
        acc += fabsf(v.x) + fabsf(v.y) + fabsf(v.z) + fabsf(v.w);
    }
    acc = wave_reduce_sum(acc);
    __shared__ float sh[4];
    if ((threadIdx.x & 63) == 0) sh[threadIdx.x >> 6] = acc;
    __syncthreads();
    if (threadIdx.x == 0) part[blockIdx.x] = sh[0] + sh[1] + sh[2] + sh[3];
}

__global__ void finalize_scales(const float* __restrict__ part1,
                                const float* __restrict__ part2,
                                float* __restrict__ scales, int nparts, float inv_n) {
    float a = 0.f, b = 0.f;
    for (int i = threadIdx.x; i < nparts; i += TPB) { a += part1[i]; b += part2[i]; }
    a = wave_reduce_sum(a);
    b = wave_reduce_sum(b);
    __shared__ float sa[4], sb[4];
    if ((threadIdx.x & 63) == 0) { sa[threadIdx.x >> 6] = a; sb[threadIdx.x >> 6] = b; }
    __syncthreads();
    if (threadIdx.x == 0) {
        scales[0] = fmaxf((sa[0] + sa[1] + sa[2] + sa[3]) * inv_n, EPSF);
        scales[1] = fmaxf((sb[0] + sb[1] + sb[2] + sb[3]) * inv_n, EPSF);
    }
}

// ---------------- weight ternarization ----------------

__global__ void quant_w_kernel(const float* __restrict__ w,
                               __hip_bfloat16* __restrict__ wq,
                               const float* __restrict__ scales, int sidx, int n4) {
    const float inv = 1.0f / scales[sidx];
    const float4* w4 = (const float4*)w;
    unsigned short* oq = (unsigned short*)wq;
    for (int i = blockIdx.x * TPB + threadIdx.x; i < n4; i += gridDim.x * TPB) {
        float4 v = w4[i];
        union { unsigned short u[4]; uint2 o; } t;
        t.u[0] = bfbits(fminf(fmaxf(rintf(v.x * inv), -1.f), 1.f));
        t.u[1] = bfbits(fminf(fmaxf(rintf(v.y * inv), -1.f), 1.f));
        t.u[2] = bfbits(fminf(fmaxf(rintf(v.z * inv), -1.f), 1.f));
        t.u[3] = bfbits(fminf(fmaxf(rintf(v.w * inv), -1.f), 1.f));
        *(uint2*)(oq + (long long)i * 4) = t.o;
    }
}

// ---------------- per-row activation quant ----------------

template <int N4PT>
__global__ void quant_rows(const float* __restrict__ in,
                           __hip_bfloat16* __restrict__ outq,
                           float* __restrict__ dq, int cols) {
    const long long row = blockIdx.x;
    const float4* r4 = (const float4*)(in + row * (long long)cols);
    float4 v[N4PT];
    float mx = 0.f;
#pragma unroll
    for (int j = 0; j < N4PT; ++j) {
        v[j] = r4[threadIdx.x + TPB * j];
        mx = fmaxf(mx, fmaxf(fmaxf(fabsf(v[j].x), fabsf(v[j].y)),
                             fmaxf(fabsf(v[j].z), fabsf(v[j].w))));
    }
    mx = wave_reduce_max(mx);
    __shared__ float sh[4];
    __shared__ float res;
    if ((threadIdx.x & 63) == 0) sh[threadIdx.x >> 6] = mx;
    __syncthreads();
    if (threadIdx.x == 0) res = fmaxf(fmaxf(sh[0], sh[1]), fmaxf(sh[2], sh[3]));
    __syncthreads();
    const float clipped = fmaxf(res, EPSF);
    const float scale = 127.f / clipped;
    if (threadIdx.x == 0) dq[row] = clipped / 127.f;
    unsigned short* oq = (unsigned short*)(outq + row * (long long)cols);
#pragma unroll
    for (int j = 0; j < N4PT; ++j) {
        const int i = threadIdx.x + TPB * j;
        union { unsigned short u[4]; uint2 w; } o;
        o.u[0] = bfbits(fminf(fmaxf(rintf(v[j].x * scale), -128.f), 127.f));
        o.u[1] = bfbits(fminf(fmaxf(rintf(v[j].y * scale), -128.f), 127.f));
        o.u[2] = bfbits(fminf(fmaxf(rintf(v[j].z * scale), -128.f), 127.f));
        o.u[3] = bfbits(fminf(fmaxf(rintf(v[j].w * scale), -128.f), 127.f));
        *(uint2*)(oq + (long long)i * 4) = o.w;
    }
}

// ---------------- 256x256 8-phase-style GEMM ----------------
// C[m,n] = (sum_k A[m,k]*B[n,k]) * dq[m] * s, optional GELU.
// BM=BN=256, BK=64, 512 thr = 8 waves (2Mx4N), per-wave 128x64 out.
// LDS 128KB: [buf2][A/B][half2][128x64 bf16]. Counted vmcnt(6), raw s_barrier,
// read-swizzle cb ^= ((row&7)<<4) realized by pre-swizzling the GLOBAL source
// (gload_lds dest must stay linear). One barrier per phase, 4 phases/K-tile.

__device__ __forceinline__ void stage_half(const char* Xb, long long rowB, int prow,
                                           int tk, char* dst, int tid, int cbs) {
    const long long gc = (long long)tk * 128 + cbs;
    const int r = tid >> 3;
    gload16(Xb + (long long)(prow + r) * rowB + gc, dst + tid * 16);
    gload16(Xb + (long long)(prow + 64 + r) * rowB + gc, dst + 8192 + tid * 16);
}

#define QUAD(MB, NB)                                                            \
    _Pragma("unroll") for (int mi = 0; mi < 4; ++mi)                            \
    _Pragma("unroll") for (int ni = 0; ni < 2; ++ni)                            \
    _Pragma("unroll") for (int ks = 0; ks < 2; ++ks)                            \
        acc[(MB)*4 + mi][(NB)*2 + ni] = __builtin_amdgcn_mfma_f32_16x16x32_bf16( \
            aq[mi][ks], bq[(NB)*2 + ni][ks], acc[(MB)*4 + mi][(NB)*2 + ni], 0, 0, 0);

#define WAITL0 do { asm volatile("s_waitcnt lgkmcnt(0)" ::: "memory"); \
                    __builtin_amdgcn_sched_barrier(0); } while (0)

template <int GELU>
__global__ __launch_bounds__(512, 2) void gemm8p(
    const __hip_bfloat16* __restrict__ A, const __hip_bfloat16* __restrict__ B,
    float* __restrict__ C, int N, int K,
    const float* __restrict__ dq, const float* __restrict__ scales, int sidx) {
    __shared__ __align__(16) char lds[131072];

    const int tid = threadIdx.x;
    const int lane = tid & 63;
    const int wid = tid >> 6;
    const int wr = wid >> 2;     // 0..1 : 128-row half
    const int wc = wid & 3;      // 0..3 : 64-col group

    const long long M0 = (long long)blockIdx.y * 256;
    const long long N0 = (long long)blockIdx.x * 256;
    const long long rb = (long long)K * 2;
    const char* Ab = (const char*)A + M0 * rb;
    const char* Bb = (const char*)B + N0 * rb;
    const int nt = K >> 6;

    // staging: linear LDS dest, pre-swizzled global source column
    const int cbs = (((tid & 7) ^ ((tid >> 3) & 7)) << 4);

    // fragment reads: swizzled LDS column
    const int l15 = lane & 15, l4 = lane >> 4;
    const int swz = (lane & 7) << 4;
    const int acb0 = (l4 * 16) ^ swz;          // ks=0
    const int acb1 = (64 + l4 * 16) ^ swz;     // ks=1
    const int aoff = wr * 16384;                               // within buf, A region
    const int boff = 32768 + (wc >> 1) * 16384 + (wc & 1) * 8192;  // B region + sub-half

    floatx4 acc[8][4] = {};
    bf16x8 aq[4][2], bq[4][2];

    // prologue: tile0 (B0,B1,A0,A1) -> buf0 ; tile1 (B0,B1,A0) -> buf1
    stage_half(Bb, rb, 0,   0, lds + 32768,         tid, cbs);
    stage_half(Bb, rb, 128, 0, lds + 32768 + 16384, tid, cbs);
    stage_half(Ab, rb, 0,   0, lds + 0,             tid, cbs);
    stage_half(Ab, rb, 128, 0, lds + 16384,         tid, cbs);
    if (nt > 1) {
        stage_half(Bb, rb, 0,   1, lds + 65536 + 32768,         tid, cbs);
        stage_half(Bb, rb, 128, 1, lds + 65536 + 32768 + 16384, tid, cbs);
        stage_half(Ab, rb, 0,   1, lds + 65536,                 tid, cbs);
        asm volatile("s_waitcnt vmcnt(6)" ::: "memory");
    } else {
        asm volatile("s_waitcnt vmcnt(0)" ::: "memory");
    }
    __builtin_amdgcn_sched_barrier(0);
    __builtin_amdgcn_s_barrier();

    for (int t = 0; t < nt; ++t) {
        char* cur = lds + ((t & 1) << 16);
        char* nxt = lds + (((t + 1) & 1) << 16);
        const bool s1 = (t + 1) < nt;
        const bool s2 = (t + 2) < nt;

        // ---- P0: read A[mh0] + B[all] from cur; stage A1(t+1)->nxt; MFMA q(0,0)
#pragma unroll
        for (int mi = 0; mi < 4; ++mi) {
            const char* p = cur + aoff + (mi * 16 + l15) * 128;
            aq[mi][0] = *(const bf16x8*)(p + acb0);
            aq[mi][1] = *(const bf16x8*)(p + acb1);
        }
#pragma unroll
        for (int ni = 0; ni < 4; ++ni) {
            const char* p = cur + boff + (ni * 16 + l15) * 128;
            bq[ni][0] = *(const bf16x8*)(p + acb0);
            bq[ni][1] = *(const bf16x8*)(p + acb1);
        }
        if (s1) stage_half(Ab, rb, 128, t + 1, nxt + 16384, tid, cbs);
        WAITL0;
        __builtin_amdgcn_s_setprio(1);
        QUAD(0, 0);
        __builtin_amdgcn_s_setprio(0);
        __builtin_amdgcn_s_barrier();

        // ---- P1: stage B0(t+2)->cur (B0 reads finished at P0); MFMA q(0,1)
        if (s2) stage_half(Bb, rb, 0, t + 2, cur + 32768, tid, cbs);
        __builtin_amdgcn_s_setprio(1);
        QUAD(0, 1);
        __builtin_amdgcn_s_setprio(0);
        __builtin_amdgcn_s_barrier();

        // ---- P2: read A[mh1]; stage B1(t+2)->cur; MFMA q(1,0)
#pragma unroll
        for (int mi = 0; mi < 4; ++mi) {
            const char* p = cur + aoff + ((mi + 4) * 16 + l15) * 128;
            aq[mi][0] = *(const bf16x8*)(p + acb0);
            aq[mi][1] = *(const bf16x8*)(p + acb1);
        }
        if (s2) stage_half(Bb, rb, 128, t + 2, cur + 32768 + 16384, tid, cbs);
        WAITL0;
        __builtin_amdgcn_s_setprio(1);
        QUAD(1, 0);
        __builtin_amdgcn_s_setprio(0);
        __builtin_amdgcn_s_barrier();

        // ---- P3: stage A0(t+2)->cur (A0 reads finished at P2); MFMA q(1,1); vmcnt
        if (s2) stage_half(Ab, rb, 0, t + 2, cur, tid, cbs);
        __builtin_amdgcn_s_setprio(1);
        QUAD(1, 1);
        __builtin_amdgcn_s_setprio(0);
        if (s2) { asm volatile("s_waitcnt vmcnt(6)" ::: "memory"); }
        else    { asm volatile("s_waitcnt vmcnt(0)" ::: "memory"); }
        __builtin_amdgcn_sched_barrier(0);
        __builtin_amdgcn_s_barrier();
    }

    // ---- epilogue: C/D layout col=lane&15, row=(lane>>4)*4+reg
    const float s = scales[sidx];
#pragma unroll
    for (int mi = 0; mi < 8; ++mi) {
#pragma unroll
        for (int r = 0; r < 4; ++r) {
            const long long m = M0 + wr * 128 + mi * 16 + l4 * 4 + r;
            const float f = dq[m] * s;
#pragma unroll
            for (int ni = 0; ni < 4; ++ni) {
                const long long n = N0 + wc * 64 + ni * 16 + l15;
                float v = acc[mi][ni][r] * f;
                if (GELU) v = 0.5f * v * (1.0f + erff(v * 0.70710678118654752440f));
                C[m * (long long)N + n] = v;
            }
        }
    }
}

// ---------------- launcher ----------------

extern "C" void kernel_launch(void* const* d_in, const int* in_sizes, int n_in,
                              void* d_out, int out_size, void* d_ws, size_t ws_size,
                              hipStream_t stream) {
    (void)n_in; (void)out_size;
    const float* x  = (const float*)d_in[0];
    const float* w1 = (const float*)d_in[1];
    const float* w2 = (const float*)d_in[2];
    float* out = (float*)d_out;

    const int D = 2048, H = 8192;
    const long long M = (long long)in_sizes[0] / D;
    const long long GROUP = 2048;
    const int nG = (int)(M / GROUP);

    char* base = (char*)d_ws;
    size_t off = 0;
    auto alloc = [&](size_t bytes) -> char* {
        char* r = base + off;
        off = (off + bytes + 255) & ~(size_t)255;
        return r;
    };

    const bool fullH = ws_size >= (size_t)310 * 1024 * 1024;

    float* part1 = (float*)alloc(2048 * 4);
    float* part2 = (float*)alloc(2048 * 4);
    float* scales = (float*)alloc(256);
    float* dqx = (float*)alloc((size_t)M * 4);
    float* dqh = (float*)alloc((size_t)M * 4);
    __hip_bfloat16* w1q = (__hip_bfloat16*)alloc((size_t)H * D * 2);
    __hip_bfloat16* w2q = (__hip_bfloat16*)alloc((size_t)H * D * 2);
    __hip_bfloat16* xq  = (__hip_bfloat16*)alloc((size_t)M * D * 2);
    __hip_bfloat16* hq  = (__hip_bfloat16*)alloc((size_t)(fullH ? M : GROUP) * H * 2);
    float* hch = (float*)alloc((size_t)GROUP * H * 4);

    const int nw4 = H * D / 4;
    abssum_partial<<<2048, TPB, 0, stream>>>(w1, nw4, part1);
    abssum_partial<<<2048, TPB, 0, stream>>>(w2, nw4, part2);
    finalize_scales<<<1, TPB, 0, stream>>>(part1, part2, scales, 2048,
                                           1.0f / (float)(H * D));
    quant_w_kernel<<<2048, TPB, 0, stream>>>(w1, w1q, scales, 0, nw4);
    quant_w_kernel<<<2048, TPB, 0, stream>>>(w2, w2q, scales, 1, nw4);
    quant_rows<2><<<(int)M, TPB, 0, stream>>>(x, xq, dqx, D);

    if (fullH) {
        for (int g = 0; g < nG; ++g) {
            const long long m0 = g * GROUP;
            gemm8p<1><<<dim3(H / 256, (int)(GROUP / 256)), 512, 0, stream>>>(
                xq + m0 * D, w1q, hch, H, D, dqx + m0, scales, 0);
            quant_rows<8><<<(int)GROUP, TPB, 0, stream>>>(hch, hq + m0 * H, dqh + m0, H);
        }
        gemm8p<0><<<dim3(D / 256, (int)(M / 256)), 512, 0, stream>>>(
            hq, w2q, out, D, H, dqh, scales, 1);
    } else {
        for (int g = 0; g < nG; ++g) {
            const long long m0 = g * GROUP;
            gemm8p<1><<<dim3(H / 256, (int)(GROUP / 256)), 512, 0, stream>>>(
                xq + m0 * D, w1q, hch, H, D, dqx + m0, scales, 0);
            quant_rows<8><<<(int)GROUP, TPB, 0, stream>>>(hch, hq, dqh, H);
            gemm8p<0><<<dim3(D / 256, (int)(GROUP / 256)), 512, 0, stream>>>(
                hq, w2q, out + m0 * D, D, H, dqh, scales, 1);
        }
    }
}

// Round 3
// 591.387 us; speedup vs baseline: 2.1119x; 1.9861x over previous
//
#include <hip/hip_runtime.h>
#include <hip/hip_bf16.h>
#include <stdint.h>

#define TPB 256
#define EPSF 1e-5f

using bf16x8  = __attribute__((ext_vector_type(8))) __bf16;
using floatx4 = __attribute__((ext_vector_type(4))) float;

// ---------------- helpers ----------------

__device__ __forceinline__ void gload16(const void* g, void* l) {
    __builtin_amdgcn_global_load_lds(
        (__attribute__((address_space(1))) void*)g,
        (__attribute__((address_space(3))) void*)l,
        16, 0, 0);
}

__device__ __forceinline__ float wave_reduce_sum(float v) {
#pragma unroll
    for (int off = 32; off > 0; off >>= 1) v += __shfl_down(v, off, 64);
    return v;
}

__device__ __forceinline__ float wave_reduce_max(float v) {
#pragma unroll
    for (int off = 32; off > 0; off >>= 1) v = fmaxf(v, __shfl_down(v, off, 64));
    return v;
}

__device__ __forceinline__ unsigned short bfbits(float f) {
    __hip_bfloat16 h = __float2bfloat16(f);  // RNE
    union { __hip_bfloat16 h; unsigned short u; } cv;
    cv.h = h;
    return cv.u;
}

__device__ __forceinline__ float f_from_bits(unsigned u) {
    union { unsigned u; float f; } cv;
    cv.u = u;
    return cv.f;
}

// ---------------- scale reduction (deterministic two-pass) ----------------

__global__ void abssum_partial(const float* __restrict__ w, int n4,
                               float* __restrict__ part) {
    const float4* w4 = (const float4*)w;
    float acc = 0.f;
    for (int i = blockIdx.x * TPB + threadIdx.x; i < n4; i += gridDim.x * TPB) {
        float4 v = w4[i];
        acc += fabsf(v.x) + fabsf(v.y) + fabsf(v.z) + fabsf(v.w);
    }
    acc = wave_reduce_sum(acc);
    __shared__ float sh[4];
    if ((threadIdx.x & 63) == 0) sh[threadIdx.x >> 6] = acc;
    __syncthreads();
    if (threadIdx.x == 0) part[blockIdx.x] = sh[0] + sh[1] + sh[2] + sh[3];
}

__global__ void finalize_scales(const float* __restrict__ part1,
                                const float* __restrict__ part2,
                                float* __restrict__ scales, int nparts, float inv_n) {
    float a = 0.f, b = 0.f;
    for (int i = threadIdx.x; i < nparts; i += TPB) { a += part1[i]; b += part2[i]; }
    a = wave_reduce_sum(a);
    b = wave_reduce_sum(b);
    __shared__ float sa[4], sb[4];
    if ((threadIdx.x & 63) == 0) { sa[threadIdx.x >> 6] = a; sb[threadIdx.x >> 6] = b; }
    __syncthreads();
    if (threadIdx.x == 0) {
        scales[0] = fmaxf((sa[0] + sa[1] + sa[2] + sa[3]) * inv_n, EPSF);
        scales[1] = fmaxf((sb[0] + sb[1] + sb[2] + sb[3]) * inv_n, EPSF);
    }
}

// ---------------- weight ternarization ----------------

__global__ void quant_w_kernel(const float* __restrict__ w,
                               __hip_bfloat16* __restrict__ wq,
                               const float* __restrict__ scales, int sidx, int n4) {
    const float inv = 1.0f / scales[sidx];
    const float4* w4 = (const float4*)w;
    unsigned short* oq = (unsigned short*)wq;
    for (int i = blockIdx.x * TPB + threadIdx.x; i < n4; i += gridDim.x * TPB) {
        float4 v = w4[i];
        union { unsigned short u[4]; uint2 o; } t;
        t.u[0] = bfbits(fminf(fmaxf(rintf(v.x * inv), -1.f), 1.f));
        t.u[1] = bfbits(fminf(fmaxf(rintf(v.y * inv), -1.f), 1.f));
        t.u[2] = bfbits(fminf(fmaxf(rintf(v.z * inv), -1.f), 1.f));
        t.u[3] = bfbits(fminf(fmaxf(rintf(v.w * inv), -1.f), 1.f));
        *(uint2*)(oq + (long long)i * 4) = t.o;
    }
}

// ---------------- per-row activation quant (fp32 input) ----------------

template <int N4PT>
__global__ void quant_rows_f32(const float* __restrict__ in,
                               __hip_bfloat16* __restrict__ outq,
                               float* __restrict__ dq, int cols) {
    const long long row = blockIdx.x;
    const float4* r4 = (const float4*)(in + row * (long long)cols);
    float4 v[N4PT];
    float mx = 0.f;
#pragma unroll
    for (int j = 0; j < N4PT; ++j) {
        v[j] = r4[threadIdx.x + TPB * j];
        mx = fmaxf(mx, fmaxf(fmaxf(fabsf(v[j].x), fabsf(v[j].y)),
                             fmaxf(fabsf(v[j].z), fabsf(v[j].w))));
    }
    mx = wave_reduce_max(mx);
    __shared__ float sh[4];
    __shared__ float res;
    if ((threadIdx.x & 63) == 0) sh[threadIdx.x >> 6] = mx;
    __syncthreads();
    if (threadIdx.x == 0) res = fmaxf(fmaxf(sh[0], sh[1]), fmaxf(sh[2], sh[3]));
    __syncthreads();
    const float clipped = fmaxf(res, EPSF);
    const float scale = 127.f / clipped;
    if (threadIdx.x == 0) dq[row] = clipped / 127.f;
    unsigned short* oq = (unsigned short*)(outq + row * (long long)cols);
#pragma unroll
    for (int j = 0; j < N4PT; ++j) {
        const int i = threadIdx.x + TPB * j;
        union { unsigned short u[4]; uint2 w; } o;
        o.u[0] = bfbits(fminf(fmaxf(rintf(v[j].x * scale), -128.f), 127.f));
        o.u[1] = bfbits(fminf(fmaxf(rintf(v[j].y * scale), -128.f), 127.f));
        o.u[2] = bfbits(fminf(fmaxf(rintf(v[j].z * scale), -128.f), 127.f));
        o.u[3] = bfbits(fminf(fmaxf(rintf(v[j].w * scale), -128.f), 127.f));
        *(uint2*)(oq + (long long)i * 4) = o.w;
    }
}

// ---------------- per-row quant, bf16 input, IN PLACE (for h) ----------------
// cols must equal TPB*8*NJ ; NJ=4 -> 8192

template <int NJ>
__global__ void quant_rows_bf16(unsigned short* __restrict__ h,
                                float* __restrict__ dq, int cols) {
    const long long row = blockIdx.x;
    unsigned short* rp = h + row * (long long)cols;
    uint4 v[NJ];
    float mx = 0.f;
#pragma unroll
    for (int j = 0; j < NJ; ++j) {
        v[j] = *(const uint4*)(rp + (threadIdx.x + TPB * j) * 8);
        const unsigned* u = (const unsigned*)&v[j];
#pragma unroll
        for (int e = 0; e < 4; ++e) {
            float lo = f_from_bits(u[e] << 16);
            float hi = f_from_bits(u[e] & 0xffff0000u);
            mx = fmaxf(mx, fmaxf(fabsf(lo), fabsf(hi)));
        }
    }
    mx = wave_reduce_max(mx);
    __shared__ float sh[4];
    __shared__ float res;
    if ((threadIdx.x & 63) == 0) sh[threadIdx.x >> 6] = mx;
    __syncthreads();
    if (threadIdx.x == 0) res = fmaxf(fmaxf(sh[0], sh[1]), fmaxf(sh[2], sh[3]));
    __syncthreads();
    const float clipped = fmaxf(res, EPSF);
    const float scale = 127.f / clipped;
    if (threadIdx.x == 0) dq[row] = clipped / 127.f;
#pragma unroll
    for (int j = 0; j < NJ; ++j) {
        const unsigned* u = (const unsigned*)&v[j];
        unsigned o[4];
#pragma unroll
        for (int e = 0; e < 4; ++e) {
            float lo = f_from_bits(u[e] << 16);
            float hi = f_from_bits(u[e] & 0xffff0000u);
            unsigned qlo = bfbits(fminf(fmaxf(rintf(lo * scale), -128.f), 127.f));
            unsigned qhi = bfbits(fminf(fmaxf(rintf(hi * scale), -128.f), 127.f));
            o[e] = qlo | (qhi << 16);
        }
        *(uint4*)(rp + (threadIdx.x + TPB * j) * 8) = *(uint4*)o;
    }
}

// ---------------- 256x256 8-phase GEMM ----------------
// C[m,n] = (sum_k A[m,k]*B[n,k]) * dq[m] * s ; GELU=1: gelu + bf16 store,
// GELU=0: fp32 store. XCD-swizzled block ids (nwg % 8 == 0 required).

__device__ __forceinline__ void stage_half(const char* Xb, long long rowB, int prow,
                                           int tk, char* dst, int tid, int cbs) {
    const long long gc = (long long)tk * 128 + cbs;
    const int r = tid >> 3;
    gload16(Xb + (long long)(prow + r) * rowB + gc, dst + tid * 16);
    gload16(Xb + (long long)(prow + 64 + r) * rowB + gc, dst + 8192 + tid * 16);
}

#define QUAD(MB, NB)                                                            \
    _Pragma("unroll") for (int mi = 0; mi < 4; ++mi)                            \
    _Pragma("unroll") for (int ni = 0; ni < 2; ++ni)                            \
    _Pragma("unroll") for (int ks = 0; ks < 2; ++ks)                            \
        acc[(MB)*4 + mi][(NB)*2 + ni] = __builtin_amdgcn_mfma_f32_16x16x32_bf16( \
            aq[mi][ks], bq[(NB)*2 + ni][ks], acc[(MB)*4 + mi][(NB)*2 + ni], 0, 0, 0);

#define WAITL0 do { asm volatile("s_waitcnt lgkmcnt(0)" ::: "memory"); \
                    __builtin_amdgcn_sched_barrier(0); } while (0)

template <int GELU>
__global__ __launch_bounds__(512, 2) void gemm8p(
    const __hip_bfloat16* __restrict__ A, const __hip_bfloat16* __restrict__ B,
    void* __restrict__ Cv, int N, int K,
    const float* __restrict__ dq, const float* __restrict__ scales, int sidx) {
    __shared__ __align__(16) char lds[131072];

    const int tid = threadIdx.x;
    const int lane = tid & 63;
    const int wid = tid >> 6;
    const int wr = wid >> 2;
    const int wc = wid & 3;

    // bijective XCD swizzle: consecutive swizzled ids land on one XCD
    const unsigned gx = gridDim.x;
    unsigned lin = blockIdx.y * gx + blockIdx.x;
    const unsigned q8 = (gx * gridDim.y) >> 3;
    lin = (lin & 7) * q8 + (lin >> 3);
    const unsigned bx = lin % gx;
    const unsigned by = lin / gx;

    const long long M0 = (long long)by * 256;
    const long long N0 = (long long)bx * 256;
    const long long rb = (long long)K * 2;
    const char* Ab = (const char*)A + M0 * rb;
    const char* Bb = (const char*)B + N0 * rb;
    const int nt = K >> 6;

    const int cbs = (((tid & 7) ^ ((tid >> 3) & 7)) << 4);

    const int l15 = lane & 15, l4 = lane >> 4;
    const int swz = (lane & 7) << 4;
    const int acb0 = (l4 * 16) ^ swz;
    const int acb1 = (64 + l4 * 16) ^ swz;
    const int aoff = wr * 16384;
    const int boff = 32768 + (wc >> 1) * 16384 + (wc & 1) * 8192;

    floatx4 acc[8][4] = {};
    bf16x8 aq[4][2], bq[4][2];

    stage_half(Bb, rb, 0,   0, lds + 32768,         tid, cbs);
    stage_half(Bb, rb, 128, 0, lds + 32768 + 16384, tid, cbs);
    stage_half(Ab, rb, 0,   0, lds + 0,             tid, cbs);
    stage_half(Ab, rb, 128, 0, lds + 16384,         tid, cbs);
    if (nt > 1) {
        stage_half(Bb, rb, 0,   1, lds + 65536 + 32768,         tid, cbs);
        stage_half(Bb, rb, 128, 1, lds + 65536 + 32768 + 16384, tid, cbs);
        stage_half(Ab, rb, 0,   1, lds + 65536,                 tid, cbs);
        asm volatile("s_waitcnt vmcnt(6)" ::: "memory");
    } else {
        asm volatile("s_waitcnt vmcnt(0)" ::: "memory");
    }
    __builtin_amdgcn_sched_barrier(0);
    __builtin_amdgcn_s_barrier();

    for (int t = 0; t < nt; ++t) {
        char* cur = lds + ((t & 1) << 16);
        char* nxt = lds + (((t + 1) & 1) << 16);
        const bool s1 = (t + 1) < nt;
        const bool s2 = (t + 2) < nt;

        // P0: read A[mh0]+B[all]; stage A1(t+1)->nxt; MFMA q(0,0)
#pragma unroll
        for (int mi = 0; mi < 4; ++mi) {
            const char* p = cur + aoff + (mi * 16 + l15) * 128;
            aq[mi][0] = *(const bf16x8*)(p + acb0);
            aq[mi][1] = *(const bf16x8*)(p + acb1);
        }
#pragma unroll
        for (int ni = 0; ni < 4; ++ni) {
            const char* p = cur + boff + (ni * 16 + l15) * 128;
            bq[ni][0] = *(const bf16x8*)(p + acb0);
            bq[ni][1] = *(const bf16x8*)(p + acb1);
        }
        if (s1) stage_half(Ab, rb, 128, t + 1, nxt + 16384, tid, cbs);
        WAITL0;
        __builtin_amdgcn_s_setprio(1);
        QUAD(0, 0);
        __builtin_amdgcn_s_setprio(0);
        __builtin_amdgcn_s_barrier();

        // P1: stage B0(t+2)->cur; MFMA q(0,1)
        if (s2) stage_half(Bb, rb, 0, t + 2, cur + 32768, tid, cbs);
        __builtin_amdgcn_s_setprio(1);
        QUAD(0, 1);
        __builtin_amdgcn_s_setprio(0);
        __builtin_amdgcn_s_barrier();

        // P2: read A[mh1]; stage B1(t+2)->cur; MFMA q(1,0)
#pragma unroll
        for (int mi = 0; mi < 4; ++mi) {
            const char* p = cur + aoff + ((mi + 4) * 16 + l15) * 128;
            aq[mi][0] = *(const bf16x8*)(p + acb0);
            aq[mi][1] = *(const bf16x8*)(p + acb1);
        }
        if (s2) stage_half(Bb, rb, 128, t + 2, cur + 32768 + 16384, tid, cbs);
        WAITL0;
        __builtin_amdgcn_s_setprio(1);
        QUAD(1, 0);
        __builtin_amdgcn_s_setprio(0);
        __builtin_amdgcn_s_barrier();

        // P3: stage A0(t+2)->cur; MFMA q(1,1); counted vmcnt
        if (s2) stage_half(Ab, rb, 0, t + 2, cur, tid, cbs);
        __builtin_amdgcn_s_setprio(1);
        QUAD(1, 1);
        __builtin_amdgcn_s_setprio(0);
        if (s2) { asm volatile("s_waitcnt vmcnt(6)" ::: "memory"); }
        else    { asm volatile("s_waitcnt vmcnt(0)" ::: "memory"); }
        __builtin_amdgcn_sched_barrier(0);
        __builtin_amdgcn_s_barrier();
    }

    // epilogue: C/D layout col=lane&15, row=(lane>>4)*4+reg
    const float s = scales[sidx];
#pragma unroll
    for (int mi = 0; mi < 8; ++mi) {
#pragma unroll
        for (int r = 0; r < 4; ++r) {
            const long long m = M0 + wr * 128 + mi * 16 + l4 * 4 + r;
            const float f = dq[m] * s;
#pragma unroll
            for (int ni = 0; ni < 4; ++ni) {
                const long long n = N0 + wc * 64 + ni * 16 + l15;
                float v = acc[mi][ni][r] * f;
                if (GELU) {
                    v = 0.5f * v * (1.0f + erff(v * 0.70710678118654752440f));
                    ((unsigned short*)Cv)[m * (long long)N + n] = bfbits(v);
                } else {
                    ((float*)Cv)[m * (long long)N + n] = v;
                }
            }
        }
    }
}

// ---------------- launcher ----------------

extern "C" void kernel_launch(void* const* d_in, const int* in_sizes, int n_in,
                              void* d_out, int out_size, void* d_ws, size_t ws_size,
                              hipStream_t stream) {
    (void)n_in; (void)out_size; (void)ws_size;
    const float* x  = (const float*)d_in[0];
    const float* w1 = (const float*)d_in[1];
    const float* w2 = (const float*)d_in[2];
    float* out = (float*)d_out;

    const int D = 2048, H = 8192;
    const long long M = (long long)in_sizes[0] / D;  // 8192

    char* base = (char*)d_ws;
    size_t off = 0;
    auto alloc = [&](size_t bytes) -> char* {
        char* r = base + off;
        off = (off + bytes + 255) & ~(size_t)255;
        return r;
    };

    // total: ~192 MiB + small (known to fit: R1/R2 footprint)
    float* part1 = (float*)alloc(2048 * 4);
    float* part2 = (float*)alloc(2048 * 4);
    float* scales = (float*)alloc(256);
    float* dqx = (float*)alloc((size_t)M * 4);
    float* dqh = (float*)alloc((size_t)M * 4);
    __hip_bfloat16* wq = (__hip_bfloat16*)alloc((size_t)H * D * 2);   // w1q then w2q
    __hip_bfloat16* xq = (__hip_bfloat16*)alloc((size_t)M * D * 2);
    unsigned short* h  = (unsigned short*)alloc((size_t)M * H * 2);   // gelu(h) bf16, re-quant in place

    const int nw4 = H * D / 4;
    abssum_partial<<<2048, TPB, 0, stream>>>(w1, nw4, part1);
    abssum_partial<<<2048, TPB, 0, stream>>>(w2, nw4, part2);
    finalize_scales<<<1, TPB, 0, stream>>>(part1, part2, scales, 2048,
                                           1.0f / (float)(H * D));
    quant_w_kernel<<<2048, TPB, 0, stream>>>(w1, wq, scales, 0, nw4);
    quant_rows_f32<2><<<(int)M, TPB, 0, stream>>>(x, xq, dqx, D);

    // GEMM1: [M x D] @ [H x D]^T -> gelu -> bf16 h   (grid 32x32 = 1024 blocks)
    gemm8p<1><<<dim3(H / 256, (int)(M / 256)), 512, 0, stream>>>(
        xq, wq, h, H, D, dqx, scales, 0);

    // per-row requant of h, in place (8192 blocks)
    quant_rows_bf16<4><<<(int)M, TPB, 0, stream>>>(h, dqh, H);

    // ternarize w2 into the same slot (w1q dead now)
    quant_w_kernel<<<2048, TPB, 0, stream>>>(w2, wq, scales, 1, nw4);

    // GEMM2: [M x H] @ [D x H]^T -> fp32 out   (grid 8x32 = 256 blocks)
    gemm8p<0><<<dim3(D / 256, (int)(M / 256)), 512, 0, stream>>>(
        (const __hip_bfloat16*)h, wq, out, D, H, dqh, scales, 1);
}

// Round 4
// 412.530 us; speedup vs baseline: 3.0275x; 1.4336x over previous
//
#include <hip/hip_runtime.h>
#include <hip/hip_bf16.h>
#include <hip/hip_fp16.h>
#include <stdint.h>

#define TPB 256
#define EPSF 1e-5f

using i32x4 = __attribute__((ext_vector_type(4))) int;

// ---------------- helpers ----------------

__device__ __forceinline__ void gload16(const void* g, void* l) {
    __builtin_amdgcn_global_load_lds(
        (__attribute__((address_space(1))) void*)g,
        (__attribute__((address_space(3))) void*)l,
        16, 0, 0);
}

__device__ __forceinline__ float wave_reduce_sum(float v) {
#pragma unroll
    for (int off = 32; off > 0; off >>= 1) v += __shfl_down(v, off, 64);
    return v;
}

__device__ __forceinline__ float wave_reduce_max(float v) {
#pragma unroll
    for (int off = 32; off > 0; off >>= 1) v = fmaxf(v, __shfl_down(v, off, 64));
    return v;
}

__device__ __forceinline__ int q8(float f, float scale, float lo, float hi) {
    return (int)fminf(fmaxf(rintf(f * scale), lo), hi);
}

// ---------------- scale reduction (deterministic two-pass) ----------------

__global__ void abssum_partial(const float* __restrict__ w, int n4,
                               float* __restrict__ part) {
    const float4* w4 = (const float4*)w;
    float acc = 0.f;
    for (int i = blockIdx.x * TPB + threadIdx.x; i < n4; i += gridDim.x * TPB) {
        float4 v = w4[i];
        acc += fabsf(v.x) + fabsf(v.y) + fabsf(v.z) + fabsf(v.w);
    }
    acc = wave_reduce_sum(acc);
    __shared__ float sh[4];
    if ((threadIdx.x & 63) == 0) sh[threadIdx.x >> 6] = acc;
    __syncthreads();
    if (threadIdx.x == 0) part[blockIdx.x] = sh[0] + sh[1] + sh[2] + sh[3];
}

__global__ void finalize_scales(const float* __restrict__ part1,
                                const float* __restrict__ part2,
                                float* __restrict__ scales, int nparts, float inv_n) {
    float a = 0.f, b = 0.f;
    for (int i = threadIdx.x; i < nparts; i += TPB) { a += part1[i]; b += part2[i]; }
    a = wave_reduce_sum(a);
    b = wave_reduce_sum(b);
    __shared__ float sa[4], sb[4];
    if ((threadIdx.x & 63) == 0) { sa[threadIdx.x >> 6] = a; sb[threadIdx.x >> 6] = b; }
    __syncthreads();
    if (threadIdx.x == 0) {
        scales[0] = fmaxf((sa[0] + sa[1] + sa[2] + sa[3]) * inv_n, EPSF);
        scales[1] = fmaxf((sb[0] + sb[1] + sb[2] + sb[3]) * inv_n, EPSF);
    }
}

// ---------------- weight ternarization -> int8 ----------------

__global__ void quant_w_i8(const float* __restrict__ w,
                           signed char* __restrict__ wq,
                           const float* __restrict__ scales, int sidx, int n4) {
    const float inv = 1.0f / scales[sidx];
    const float4* w4 = (const float4*)w;
    unsigned* oq = (unsigned*)wq;
    for (int i = blockIdx.x * TPB + threadIdx.x; i < n4; i += gridDim.x * TPB) {
        float4 v = w4[i];
        unsigned p = ((unsigned)(q8(v.x, inv, -1.f, 1.f) & 0xff)) |
                     ((unsigned)(q8(v.y, inv, -1.f, 1.f) & 0xff) << 8) |
                     ((unsigned)(q8(v.z, inv, -1.f, 1.f) & 0xff) << 16) |
                     ((unsigned)(q8(v.w, inv, -1.f, 1.f) & 0xff) << 24);
        oq[i] = p;
    }
}

// ---------------- per-row activation quant: fp32 -> int8 ----------------

template <int NF4>  // float4s per thread; cols = NF4*TPB*4
__global__ void quant_x_i8(const float* __restrict__ in,
                           signed char* __restrict__ outq,
                           float* __restrict__ dq, int cols) {
    const long long row = blockIdx.x;
    const float4* r4 = (const float4*)(in + row * (long long)cols);
    float4 v[NF4];
    float mx = 0.f;
#pragma unroll
    for (int j = 0; j < NF4; ++j) {
        v[j] = r4[threadIdx.x + TPB * j];
        mx = fmaxf(mx, fmaxf(fmaxf(fabsf(v[j].x), fabsf(v[j].y)),
                             fmaxf(fabsf(v[j].z), fabsf(v[j].w))));
    }
    mx = wave_reduce_max(mx);
    __shared__ float sh[4];
    __shared__ float res;
    if ((threadIdx.x & 63) == 0) sh[threadIdx.x >> 6] = mx;
    __syncthreads();
    if (threadIdx.x == 0) res = fmaxf(fmaxf(sh[0], sh[1]), fmaxf(sh[2], sh[3]));
    __syncthreads();
    const float clipped = fmaxf(res, EPSF);
    const float scale = 127.f / clipped;
    if (threadIdx.x == 0) dq[row] = clipped / 127.f;
    unsigned* oq = (unsigned*)(outq + row * (long long)cols);
#pragma unroll
    for (int j = 0; j < NF4; ++j) {
        unsigned p = ((unsigned)(q8(v[j].x, scale, -128.f, 127.f) & 0xff)) |
                     ((unsigned)(q8(v[j].y, scale, -128.f, 127.f) & 0xff) << 8) |
                     ((unsigned)(q8(v[j].z, scale, -128.f, 127.f) & 0xff) << 16) |
                     ((unsigned)(q8(v[j].w, scale, -128.f, 127.f) & 0xff) << 24);
        oq[threadIdx.x + TPB * j] = p;
    }
}

// ---------------- per-row quant: fp16 -> int8 (for h) ----------------
// cols = NJ*TPB*8 ; NJ=4 -> 8192

template <int NJ>
__global__ void quant_h_i8(const unsigned short* __restrict__ h,
                           signed char* __restrict__ outq,
                           float* __restrict__ dq, int cols) {
    const long long row = blockIdx.x;
    const unsigned short* rp = h + row * (long long)cols;
    uint4 v[NJ];
    float mx = 0.f;
#pragma unroll
    for (int j = 0; j < NJ; ++j) {
        v[j] = *(const uint4*)(rp + (threadIdx.x + TPB * j) * 8);
        const unsigned* u = (const unsigned*)&v[j];
#pragma unroll
        for (int e = 0; e < 4; ++e) {
            float2 f2 = __half22float2(*(const __half2*)&u[e]);
            mx = fmaxf(mx, fmaxf(fabsf(f2.x), fabsf(f2.y)));
        }
    }
    mx = wave_reduce_max(mx);
    __shared__ float sh[4];
    __shared__ float res;
    if ((threadIdx.x & 63) == 0) sh[threadIdx.x >> 6] = mx;
    __syncthreads();
    if (threadIdx.x == 0) res = fmaxf(fmaxf(sh[0], sh[1]), fmaxf(sh[2], sh[3]));
    __syncthreads();
    const float clipped = fmaxf(res, EPSF);
    const float scale = 127.f / clipped;
    if (threadIdx.x == 0) dq[row] = clipped / 127.f;
    uint2* oq = (uint2*)(outq + row * (long long)cols);
#pragma unroll
    for (int j = 0; j < NJ; ++j) {
        const unsigned* u = (const unsigned*)&v[j];
        unsigned o[2] = {0, 0};
#pragma unroll
        for (int e = 0; e < 4; ++e) {
            float2 f2 = __half22float2(*(const __half2*)&u[e]);
            unsigned b0 = (unsigned)(q8(f2.x, scale, -128.f, 127.f) & 0xff);
            unsigned b1 = (unsigned)(q8(f2.y, scale, -128.f, 127.f) & 0xff);
            o[e >> 1] |= (b0 | (b1 << 8)) << ((e & 1) * 16);
        }
        oq[threadIdx.x + TPB * j] = *(uint2*)o;
    }
}

// ---------------- 256x256 8-phase i8 GEMM ----------------
// C[m,n] = (sum_k A[m,k]*B[n,k]) * dq[m] * s ; OUT=1: gelu + fp16 store,
// OUT=0: fp32 store. BK=128 i8 (128B rows — byte-geometry identical to the
// verified bf16 kernel). XCD-swizzled (nwg % 8 == 0 required).

__device__ __forceinline__ void stage_half(const char* Xb, long long rowB, int prow,
                                           int tk, char* dst, int tid, int cbs) {
    const long long gc = (long long)tk * 128 + cbs;
    const int r = tid >> 3;
    gload16(Xb + (long long)(prow + r) * rowB + gc, dst + tid * 16);
    gload16(Xb + (long long)(prow + 64 + r) * rowB + gc, dst + 8192 + tid * 16);
}

#define QUAD(MB, NB)                                                            \
    _Pragma("unroll") for (int mi = 0; mi < 4; ++mi)                            \
    _Pragma("unroll") for (int ni = 0; ni < 2; ++ni)                            \
    _Pragma("unroll") for (int ks = 0; ks < 2; ++ks)                            \
        acc[(MB)*4 + mi][(NB)*2 + ni] = __builtin_amdgcn_mfma_i32_16x16x64_i8(  \
            aq[mi][ks], bq[(NB)*2 + ni][ks], acc[(MB)*4 + mi][(NB)*2 + ni], 0, 0, 0);

#define WAITL0 do { asm volatile("s_waitcnt lgkmcnt(0)" ::: "memory"); \
                    __builtin_amdgcn_sched_barrier(0); } while (0)

template <int OUT>
__global__ __launch_bounds__(512, 2) void gemm8p_i8(
    const signed char* __restrict__ A, const signed char* __restrict__ B,
    void* __restrict__ Cv, int N, int K,
    const float* __restrict__ dq, const float* __restrict__ scales, int sidx) {
    __shared__ __align__(16) char lds[131072];

    const int tid = threadIdx.x;
    const int lane = tid & 63;
    const int wid = tid >> 6;
    const int wr = wid >> 2;
    const int wc = wid & 3;

    const unsigned gx = gridDim.x;
    unsigned lin = blockIdx.y * gx + blockIdx.x;
    const unsigned qq = (gx * gridDim.y) >> 3;
    lin = (lin & 7) * qq + (lin >> 3);
    const unsigned bx = lin % gx;
    const unsigned by = lin / gx;

    const long long M0 = (long long)by * 256;
    const long long N0 = (long long)bx * 256;
    const long long rb = (long long)K;  // bytes per row (i8)
    const char* Ab = (const char*)A + M0 * rb;
    const char* Bb = (const char*)B + N0 * rb;
    const int nt = K >> 7;  // 128 i8 per K-tile

    const int cbs = (((tid & 7) ^ ((tid >> 3) & 7)) << 4);

    const int l15 = lane & 15, l4 = lane >> 4;
    const int swz = (lane & 7) << 4;
    const int acb0 = (l4 * 16) ^ swz;         // ks=0: k 0..63
    const int acb1 = (64 + l4 * 16) ^ swz;    // ks=1: k 64..127
    const int aoff = wr * 16384;
    const int boff = 32768 + (wc >> 1) * 16384 + (wc & 1) * 8192;

    i32x4 acc[8][4] = {};
    i32x4 aq[4][2], bq[4][2];

    stage_half(Bb, rb, 0,   0, lds + 32768,         tid, cbs);
    stage_half(Bb, rb, 128, 0, lds + 32768 + 16384, tid, cbs);
    stage_half(Ab, rb, 0,   0, lds + 0,             tid, cbs);
    stage_half(Ab, rb, 128, 0, lds + 16384,         tid, cbs);
    if (nt > 1) {
        stage_half(Bb, rb, 0,   1, lds + 65536 + 32768,         tid, cbs);
        stage_half(Bb, rb, 128, 1, lds + 65536 + 32768 + 16384, tid, cbs);
        stage_half(Ab, rb, 0,   1, lds + 65536,                 tid, cbs);
        asm volatile("s_waitcnt vmcnt(6)" ::: "memory");
    } else {
        asm volatile("s_waitcnt vmcnt(0)" ::: "memory");
    }
    __builtin_amdgcn_sched_barrier(0);
    __builtin_amdgcn_s_barrier();

    for (int t = 0; t < nt; ++t) {
        char* cur = lds + ((t & 1) << 16);
        char* nxt = lds + (((t + 1) & 1) << 16);
        const bool s1 = (t + 1) < nt;
        const bool s2 = (t + 2) < nt;

        // P0: read A[mh0]+B[all]; stage A1(t+1)->nxt; MFMA q(0,0)
#pragma unroll
        for (int mi = 0; mi < 4; ++mi) {
            const char* p = cur + aoff + (mi * 16 + l15) * 128;
            aq[mi][0] = *(const i32x4*)(p + acb0);
            aq[mi][1] = *(const i32x4*)(p + acb1);
        }
#pragma unroll
        for (int ni = 0; ni < 4; ++ni) {
            const char* p = cur + boff + (ni * 16 + l15) * 128;
            bq[ni][0] = *(const i32x4*)(p + acb0);
            bq[ni][1] = *(const i32x4*)(p + acb1);
        }
        if (s1) stage_half(Ab, rb, 128, t + 1, nxt + 16384, tid, cbs);
        WAITL0;
        __builtin_amdgcn_s_setprio(1);
        QUAD(0, 0);
        __builtin_amdgcn_s_setprio(0);
        __builtin_amdgcn_s_barrier();

        // P1: stage B0(t+2)->cur; MFMA q(0,1)
        if (s2) stage_half(Bb, rb, 0, t + 2, cur + 32768, tid, cbs);
        __builtin_amdgcn_s_setprio(1);
        QUAD(0, 1);
        __builtin_amdgcn_s_setprio(0);
        __builtin_amdgcn_s_barrier();

        // P2: read A[mh1]; stage B1(t+2)->cur; MFMA q(1,0)
#pragma unroll
        for (int mi = 0; mi < 4; ++mi) {
            const char* p = cur + aoff + ((mi + 4) * 16 + l15) * 128;
            aq[mi][0] = *(const i32x4*)(p + acb0);
            aq[mi][1] = *(const i32x4*)(p + acb1);
        }
        if (s2) stage_half(Bb, rb, 128, t + 2, cur + 32768 + 16384, tid, cbs);
        WAITL0;
        __builtin_amdgcn_s_setprio(1);
        QUAD(1, 0);
        __builtin_amdgcn_s_setprio(0);
        __builtin_amdgcn_s_barrier();

        // P3: stage A0(t+2)->cur; MFMA q(1,1); counted vmcnt
        if (s2) stage_half(Ab, rb, 0, t + 2, cur, tid, cbs);
        __builtin_amdgcn_s_setprio(1);
        QUAD(1, 1);
        __builtin_amdgcn_s_setprio(0);
        if (s2) { asm volatile("s_waitcnt vmcnt(6)" ::: "memory"); }
        else    { asm volatile("s_waitcnt vmcnt(0)" ::: "memory"); }
        __builtin_amdgcn_sched_barrier(0);
        __builtin_amdgcn_s_barrier();
    }

    // epilogue: C/D layout col=lane&15, row=(lane>>4)*4+reg (dtype-independent)
    const float s = scales[sidx];
#pragma unroll
    for (int mi = 0; mi < 8; ++mi) {
#pragma unroll
        for (int r = 0; r < 4; ++r) {
            const long long m = M0 + wr * 128 + mi * 16 + l4 * 4 + r;
            const float f = dq[m] * s;
#pragma unroll
            for (int ni = 0; ni < 4; ++ni) {
                const long long n = N0 + wc * 64 + ni * 16 + l15;
                float v = (float)acc[mi][ni][r] * f;
                if (OUT) {
                    v = 0.5f * v * (1.0f + erff(v * 0.70710678118654752440f));
                    __half hh = __float2half(v);
                    ((unsigned short*)Cv)[m * (long long)N + n] =
                        *(const unsigned short*)&hh;
                } else {
                    ((float*)Cv)[m * (long long)N + n] = v;
                }
            }
        }
    }
}

// ---------------- launcher ----------------

extern "C" void kernel_launch(void* const* d_in, const int* in_sizes, int n_in,
                              void* d_out, int out_size, void* d_ws, size_t ws_size,
                              hipStream_t stream) {
    (void)n_in; (void)out_size; (void)ws_size;
    const float* x  = (const float*)d_in[0];
    const float* w1 = (const float*)d_in[1];
    const float* w2 = (const float*)d_in[2];
    float* out = (float*)d_out;

    const int D = 2048, H = 8192;
    const long long M = (long long)in_sizes[0] / D;  // 8192
    const long long MC = M / 2;                      // 4096-row h chunks

    char* base = (char*)d_ws;
    size_t off = 0;
    auto alloc = [&](size_t bytes) -> char* {
        char* r = base + off;
        off = (off + bytes + 255) & ~(size_t)255;
        return r;
    };

    // ~160 MiB total (well under the proven 196 MiB footprint)
    float* part1 = (float*)alloc(2048 * 4);
    float* part2 = (float*)alloc(2048 * 4);
    float* scales = (float*)alloc(256);
    float* dqx = (float*)alloc((size_t)M * 4);
    float* dqh = (float*)alloc((size_t)M * 4);
    signed char* wq = (signed char*)alloc((size_t)H * D);      // w1 then w2 overlay
    signed char* xq = (signed char*)alloc((size_t)M * D);
    signed char* hq = (signed char*)alloc((size_t)M * H);      // int8 h (full)
    unsigned short* hf = (unsigned short*)alloc((size_t)MC * H * 2);  // fp16 h chunk

    const int nw4 = H * D / 4;
    abssum_partial<<<2048, TPB, 0, stream>>>(w1, nw4, part1);
    abssum_partial<<<2048, TPB, 0, stream>>>(w2, nw4, part2);
    finalize_scales<<<1, TPB, 0, stream>>>(part1, part2, scales, 2048,
                                           1.0f / (float)(H * D));
    quant_w_i8<<<2048, TPB, 0, stream>>>(w1, wq, scales, 0, nw4);
    quant_x_i8<2><<<(int)M, TPB, 0, stream>>>(x, xq, dqx, D);

    for (int g = 0; g < 2; ++g) {
        const long long m0 = g * MC;
        // GEMM1 chunk: [MC x D] @ [H x D]^T -> gelu -> fp16   (grid 32x16 = 512)
        gemm8p_i8<1><<<dim3(H / 256, (int)(MC / 256)), 512, 0, stream>>>(
            xq + m0 * D, wq, hf, H, D, dqx + m0, scales, 0);
        // requant fp16 -> int8 rows
        quant_h_i8<4><<<(int)MC, TPB, 0, stream>>>(hf, hq + m0 * H, dqh + m0, H);
    }

    // ternarize w2 into the same slot (w1q dead now)
    quant_w_i8<<<2048, TPB, 0, stream>>>(w2, wq, scales, 1, nw4);

    // GEMM2: [M x H] @ [D x H]^T -> fp32 out   (grid 8x32 = 256 blocks)
    gemm8p_i8<0><<<dim3(D / 256, (int)(M / 256)), 512, 0, stream>>>(
        hq, wq, out, D, H, dqh, scales, 1);
}

// Round 5
// 408.115 us; speedup vs baseline: 3.0602x; 1.0108x over previous
//
#include <hip/hip_runtime.h>
#include <hip/hip_bf16.h>
#include <hip/hip_fp16.h>
#include <stdint.h>

#define TPB 256
#define EPSF 1e-5f

using i32x4 = __attribute__((ext_vector_type(4))) int;

// ---------------- helpers ----------------

__device__ __forceinline__ void gload16(const void* g, void* l) {
    __builtin_amdgcn_global_load_lds(
        (__attribute__((address_space(1))) void*)g,
        (__attribute__((address_space(3))) void*)l,
        16, 0, 0);
}

__device__ __forceinline__ float wave_reduce_sum(float v) {
#pragma unroll
    for (int off = 32; off > 0; off >>= 1) v += __shfl_down(v, off, 64);
    return v;
}

__device__ __forceinline__ float wave_reduce_max(float v) {
#pragma unroll
    for (int off = 32; off > 0; off >>= 1) v = fmaxf(v, __shfl_down(v, off, 64));
    return v;
}

__device__ __forceinline__ int q8(float f, float scale, float lo, float hi) {
    return (int)fminf(fmaxf(rintf(f * scale), lo), hi);
}

// ---------------- scale reduction (deterministic two-pass) ----------------

__global__ void abssum_partial(const float* __restrict__ w, int n4,
                               float* __restrict__ part) {
    const float4* w4 = (const float4*)w;
    float acc = 0.f;
    for (int i = blockIdx.x * TPB + threadIdx.x; i < n4; i += gridDim.x * TPB) {
        float4 v = w4[i];
        acc += fabsf(v.x) + fabsf(v.y) + fabsf(v.z) + fabsf(v.w);
    }
    acc = wave_reduce_sum(acc);
    __shared__ float sh[4];
    if ((threadIdx.x & 63) == 0) sh[threadIdx.x >> 6] = acc;
    __syncthreads();
    if (threadIdx.x == 0) part[blockIdx.x] = sh[0] + sh[1] + sh[2] + sh[3];
}

__global__ void finalize_scales(const float* __restrict__ part1,
                                const float* __restrict__ part2,
                                float* __restrict__ scales, int nparts, float inv_n) {
    float a = 0.f, b = 0.f;
    for (int i = threadIdx.x; i < nparts; i += TPB) { a += part1[i]; b += part2[i]; }
    a = wave_reduce_sum(a);
    b = wave_reduce_sum(b);
    __shared__ float sa[4], sb[4];
    if ((threadIdx.x & 63) == 0) { sa[threadIdx.x >> 6] = a; sb[threadIdx.x >> 6] = b; }
    __syncthreads();
    if (threadIdx.x == 0) {
        scales[0] = fmaxf((sa[0] + sa[1] + sa[2] + sa[3]) * inv_n, EPSF);
        scales[1] = fmaxf((sb[0] + sb[1] + sb[2] + sb[3]) * inv_n, EPSF);
    }
}

// ---------------- weight ternarization -> int8 ----------------

__global__ void quant_w_i8(const float* __restrict__ w,
                           signed char* __restrict__ wq,
                           const float* __restrict__ scales, int sidx, int n4) {
    const float inv = 1.0f / scales[sidx];
    const float4* w4 = (const float4*)w;
    unsigned* oq = (unsigned*)wq;
    for (int i = blockIdx.x * TPB + threadIdx.x; i < n4; i += gridDim.x * TPB) {
        float4 v = w4[i];
        unsigned p = ((unsigned)(q8(v.x, inv, -1.f, 1.f) & 0xff)) |
                     ((unsigned)(q8(v.y, inv, -1.f, 1.f) & 0xff) << 8) |
                     ((unsigned)(q8(v.z, inv, -1.f, 1.f) & 0xff) << 16) |
                     ((unsigned)(q8(v.w, inv, -1.f, 1.f) & 0xff) << 24);
        oq[i] = p;
    }
}

// ---------------- per-row activation quant: fp32 -> int8 ----------------

template <int NF4>  // float4s per thread; cols = NF4*TPB*4
__global__ void quant_x_i8(const float* __restrict__ in,
                           signed char* __restrict__ outq,
                           float* __restrict__ dq, int cols) {
    const long long row = blockIdx.x;
    const float4* r4 = (const float4*)(in + row * (long long)cols);
    float4 v[NF4];
    float mx = 0.f;
#pragma unroll
    for (int j = 0; j < NF4; ++j) {
        v[j] = r4[threadIdx.x + TPB * j];
        mx = fmaxf(mx, fmaxf(fmaxf(fabsf(v[j].x), fabsf(v[j].y)),
                             fmaxf(fabsf(v[j].z), fabsf(v[j].w))));
    }
    mx = wave_reduce_max(mx);
    __shared__ float sh[4];
    __shared__ float res;
    if ((threadIdx.x & 63) == 0) sh[threadIdx.x >> 6] = mx;
    __syncthreads();
    if (threadIdx.x == 0) res = fmaxf(fmaxf(sh[0], sh[1]), fmaxf(sh[2], sh[3]));
    __syncthreads();
    const float clipped = fmaxf(res, EPSF);
    const float scale = 127.f / clipped;
    if (threadIdx.x == 0) dq[row] = clipped / 127.f;
    unsigned* oq = (unsigned*)(outq + row * (long long)cols);
#pragma unroll
    for (int j = 0; j < NF4; ++j) {
        unsigned p = ((unsigned)(q8(v[j].x, scale, -128.f, 127.f) & 0xff)) |
                     ((unsigned)(q8(v[j].y, scale, -128.f, 127.f) & 0xff) << 8) |
                     ((unsigned)(q8(v[j].z, scale, -128.f, 127.f) & 0xff) << 16) |
                     ((unsigned)(q8(v[j].w, scale, -128.f, 127.f) & 0xff) << 24);
        oq[threadIdx.x + TPB * j] = p;
    }
}

// ---------------- per-row quant: fp16 -> int8 (for h) ----------------
// cols = NJ*TPB*8 ; NJ=4 -> 8192

template <int NJ>
__global__ void quant_h_i8(const unsigned short* __restrict__ h,
                           signed char* __restrict__ outq,
                           float* __restrict__ dq, int cols) {
    const long long row = blockIdx.x;
    const unsigned short* rp = h + row * (long long)cols;
    uint4 v[NJ];
    float mx = 0.f;
#pragma unroll
    for (int j = 0; j < NJ; ++j) {
        v[j] = *(const uint4*)(rp + (threadIdx.x + TPB * j) * 8);
        const unsigned* u = (const unsigned*)&v[j];
#pragma unroll
        for (int e = 0; e < 4; ++e) {
            float2 f2 = __half22float2(*(const __half2*)&u[e]);
            mx = fmaxf(mx, fmaxf(fabsf(f2.x), fabsf(f2.y)));
        }
    }
    mx = wave_reduce_max(mx);
    __shared__ float sh[4];
    __shared__ float res;
    if ((threadIdx.x & 63) == 0) sh[threadIdx.x >> 6] = mx;
    __syncthreads();
    if (threadIdx.x == 0) res = fmaxf(fmaxf(sh[0], sh[1]), fmaxf(sh[2], sh[3]));
    __syncthreads();
    const float clipped = fmaxf(res, EPSF);
    const float scale = 127.f / clipped;
    if (threadIdx.x == 0) dq[row] = clipped / 127.f;
    uint2* oq = (uint2*)(outq + row * (long long)cols);
#pragma unroll
    for (int j = 0; j < NJ; ++j) {
        const unsigned* u = (const unsigned*)&v[j];
        unsigned o[2] = {0, 0};
#pragma unroll
        for (int e = 0; e < 4; ++e) {
            float2 f2 = __half22float2(*(const __half2*)&u[e]);
            unsigned b0 = (unsigned)(q8(f2.x, scale, -128.f, 127.f) & 0xff);
            unsigned b1 = (unsigned)(q8(f2.y, scale, -128.f, 127.f) & 0xff);
            o[e >> 1] |= (b0 | (b1 << 8)) << ((e & 1) * 16);
        }
        oq[threadIdx.x + TPB * j] = *(uint2*)o;
    }
}

// ---------------- 256x256 8-phase i8 GEMM ----------------
// C[m,n] = (sum_k A[m,k]*B[n,k]) * dq[m] * s ; OUT=1: gelu + fp16 nt-store,
// OUT=0: fp32 nt-store. BK=128 i8. XCD-swizzled (nwg % 8 == 0 required).
// NOTE: no explicit lgkmcnt — ds_reads are compiler-visible loads; hipcc
// emits fine-grained counted lgkmcnt before each MFMA (m97 evidence).
// Only vmcnt (gload_lds deps, invisible to compiler) is asm-pinned.

__device__ __forceinline__ void stage_half(const char* Xb, long long rowB, int prow,
                                           int tk, char* dst, int tid, int cbs) {
    const long long gc = (long long)tk * 128 + cbs;
    const int r = tid >> 3;
    gload16(Xb + (long long)(prow + r) * rowB + gc, dst + tid * 16);
    gload16(Xb + (long long)(prow + 64 + r) * rowB + gc, dst + 8192 + tid * 16);
}

#define QUAD(MB, NB)                                                            \
    _Pragma("unroll") for (int mi = 0; mi < 4; ++mi)                            \
    _Pragma("unroll") for (int ni = 0; ni < 2; ++ni)                            \
    _Pragma("unroll") for (int ks = 0; ks < 2; ++ks)                            \
        acc[(MB)*4 + mi][(NB)*2 + ni] = __builtin_amdgcn_mfma_i32_16x16x64_i8(  \
            aq[mi][ks], bq[(NB)*2 + ni][ks], acc[(MB)*4 + mi][(NB)*2 + ni], 0, 0, 0);

template <int OUT>
__global__ __launch_bounds__(512, 2) void gemm8p_i8(
    const signed char* __restrict__ A, const signed char* __restrict__ B,
    void* __restrict__ Cv, int N, int K,
    const float* __restrict__ dq, const float* __restrict__ scales, int sidx) {
    __shared__ __align__(16) char lds[131072];

    const int tid = threadIdx.x;
    const int lane = tid & 63;
    const int wid = tid >> 6;
    const int wr = wid >> 2;
    const int wc = wid & 3;

    const unsigned gx = gridDim.x;
    unsigned lin = blockIdx.y * gx + blockIdx.x;
    const unsigned qq = (gx * gridDim.y) >> 3;
    lin = (lin & 7) * qq + (lin >> 3);
    const unsigned bx = lin % gx;
    const unsigned by = lin / gx;

    const long long M0 = (long long)by * 256;
    const long long N0 = (long long)bx * 256;
    const long long rb = (long long)K;  // bytes per row (i8)
    const char* Ab = (const char*)A + M0 * rb;
    const char* Bb = (const char*)B + N0 * rb;
    const int nt = K >> 7;  // 128 i8 per K-tile

    const int cbs = (((tid & 7) ^ ((tid >> 3) & 7)) << 4);

    const int l15 = lane & 15, l4 = lane >> 4;
    const int swz = (lane & 7) << 4;
    const int acb0 = (l4 * 16) ^ swz;         // ks=0: k 0..63
    const int acb1 = (64 + l4 * 16) ^ swz;    // ks=1: k 64..127
    const int aoff = wr * 16384;
    const int boff = 32768 + (wc >> 1) * 16384 + (wc & 1) * 8192;

    i32x4 acc[8][4] = {};
    i32x4 aq[4][2], bq[4][2];

    stage_half(Bb, rb, 0,   0, lds + 32768,         tid, cbs);
    stage_half(Bb, rb, 128, 0, lds + 32768 + 16384, tid, cbs);
    stage_half(Ab, rb, 0,   0, lds + 0,             tid, cbs);
    stage_half(Ab, rb, 128, 0, lds + 16384,         tid, cbs);
    if (nt > 1) {
        stage_half(Bb, rb, 0,   1, lds + 65536 + 32768,         tid, cbs);
        stage_half(Bb, rb, 128, 1, lds + 65536 + 32768 + 16384, tid, cbs);
        stage_half(Ab, rb, 0,   1, lds + 65536,                 tid, cbs);
        asm volatile("s_waitcnt vmcnt(6)" ::: "memory");
    } else {
        asm volatile("s_waitcnt vmcnt(0)" ::: "memory");
    }
    __builtin_amdgcn_sched_barrier(0);
    __builtin_amdgcn_s_barrier();

    for (int t = 0; t < nt; ++t) {
        char* cur = lds + ((t & 1) << 16);
        char* nxt = lds + (((t + 1) & 1) << 16);
        const bool s1 = (t + 1) < nt;
        const bool s2 = (t + 2) < nt;

        // P0: read A[mh0]+B[all]; stage A1(t+1)->nxt; MFMA q(0,0)
#pragma unroll
        for (int mi = 0; mi < 4; ++mi) {
            const char* p = cur + aoff + (mi * 16 + l15) * 128;
            aq[mi][0] = *(const i32x4*)(p + acb0);
            aq[mi][1] = *(const i32x4*)(p + acb1);
        }
#pragma unroll
        for (int ni = 0; ni < 4; ++ni) {
            const char* p = cur + boff + (ni * 16 + l15) * 128;
            bq[ni][0] = *(const i32x4*)(p + acb0);
            bq[ni][1] = *(const i32x4*)(p + acb1);
        }
        if (s1) stage_half(Ab, rb, 128, t + 1, nxt + 16384, tid, cbs);
        __builtin_amdgcn_s_setprio(1);
        QUAD(0, 0);
        __builtin_amdgcn_s_setprio(0);
        __builtin_amdgcn_s_barrier();

        // P1: stage B0(t+2)->cur; MFMA q(0,1)
        if (s2) stage_half(Bb, rb, 0, t + 2, cur + 32768, tid, cbs);
        __builtin_amdgcn_s_setprio(1);
        QUAD(0, 1);
        __builtin_amdgcn_s_setprio(0);
        __builtin_amdgcn_s_barrier();

        // P2: read A[mh1]; stage B1(t+2)->cur; MFMA q(1,0)
#pragma unroll
        for (int mi = 0; mi < 4; ++mi) {
            const char* p = cur + aoff + ((mi + 4) * 16 + l15) * 128;
            aq[mi][0] = *(const i32x4*)(p + acb0);
            aq[mi][1] = *(const i32x4*)(p + acb1);
        }
        if (s2) stage_half(Bb, rb, 128, t + 2, cur + 32768 + 16384, tid, cbs);
        __builtin_amdgcn_s_setprio(1);
        QUAD(1, 0);
        __builtin_amdgcn_s_setprio(0);
        __builtin_amdgcn_s_barrier();

        // P3: stage A0(t+2)->cur; MFMA q(1,1); counted vmcnt
        if (s2) stage_half(Ab, rb, 0, t + 2, cur, tid, cbs);
        __builtin_amdgcn_s_setprio(1);
        QUAD(1, 1);
        __builtin_amdgcn_s_setprio(0);
        if (s2) { asm volatile("s_waitcnt vmcnt(6)" ::: "memory"); }
        else    { asm volatile("s_waitcnt vmcnt(0)" ::: "memory"); }
        __builtin_amdgcn_sched_barrier(0);
        __builtin_amdgcn_s_barrier();
    }

    // epilogue: C/D layout col=lane&15, row=(lane>>4)*4+reg (dtype-independent)
    const float s = scales[sidx];
#pragma unroll
    for (int mi = 0; mi < 8; ++mi) {
#pragma unroll
        for (int r = 0; r < 4; ++r) {
            const long long m = M0 + wr * 128 + mi * 16 + l4 * 4 + r;
            const float f = dq[m] * s;
#pragma unroll
            for (int ni = 0; ni < 4; ++ni) {
                const long long n = N0 + wc * 64 + ni * 16 + l15;
                float v = (float)acc[mi][ni][r] * f;
                if (OUT) {
                    v = 0.5f * v * (1.0f + erff(v * 0.70710678118654752440f));
                    __half hh = __float2half(v);
                    __builtin_nontemporal_store(
                        *(const unsigned short*)&hh,
                        (unsigned short*)Cv + m * (long long)N + n);
                } else {
                    __builtin_nontemporal_store(
                        v, (float*)Cv + m * (long long)N + n);
                }
            }
        }
    }
}

// ---------------- launcher ----------------

extern "C" void kernel_launch(void* const* d_in, const int* in_sizes, int n_in,
                              void* d_out, int out_size, void* d_ws, size_t ws_size,
                              hipStream_t stream) {
    (void)n_in; (void)out_size;
    const float* x  = (const float*)d_in[0];
    const float* w1 = (const float*)d_in[1];
    const float* w2 = (const float*)d_in[2];
    float* out = (float*)d_out;

    const int D = 2048, H = 8192;
    const long long M = (long long)in_sizes[0] / D;  // 8192

    char* base = (char*)d_ws;
    size_t off = 0;
    auto alloc = [&](size_t bytes) -> char* {
        char* r = base + off;
        off = (off + bytes + 255) & ~(size_t)255;
        return r;
    };

    // full-M plan: ~231 MiB ; chunked plan: ~164 MiB (proven fits)
    const bool fullM = ws_size >= (size_t)236 * 1024 * 1024;
    const long long MC = fullM ? M : M / 2;

    float* part1 = (float*)alloc(2048 * 4);
    float* part2 = (float*)alloc(2048 * 4);
    float* scales = (float*)alloc(256);
    float* dqx = (float*)alloc((size_t)M * 4);
    float* dqh = (float*)alloc((size_t)M * 4);
    signed char* wq = (signed char*)alloc((size_t)H * D);      // w1 then w2 overlay
    signed char* xq = (signed char*)alloc((size_t)M * D);
    signed char* hq = (signed char*)alloc((size_t)M * H);      // int8 h (full)
    unsigned short* hf = (unsigned short*)alloc((size_t)MC * H * 2);  // fp16 h

    const int nw4 = H * D / 4;
    abssum_partial<<<2048, TPB, 0, stream>>>(w1, nw4, part1);
    abssum_partial<<<2048, TPB, 0, stream>>>(w2, nw4, part2);
    finalize_scales<<<1, TPB, 0, stream>>>(part1, part2, scales, 2048,
                                           1.0f / (float)(H * D));
    quant_w_i8<<<2048, TPB, 0, stream>>>(w1, wq, scales, 0, nw4);
    quant_x_i8<2><<<(int)M, TPB, 0, stream>>>(x, xq, dqx, D);

    if (fullM) {
        gemm8p_i8<1><<<dim3(H / 256, (int)(M / 256)), 512, 0, stream>>>(
            xq, wq, hf, H, D, dqx, scales, 0);
        quant_h_i8<4><<<(int)M, TPB, 0, stream>>>(hf, hq, dqh, H);
    } else {
        for (int g = 0; g < 2; ++g) {
            const long long m0 = g * MC;
            gemm8p_i8<1><<<dim3(H / 256, (int)(MC / 256)), 512, 0, stream>>>(
                xq + m0 * D, wq, hf, H, D, dqx + m0, scales, 0);
            quant_h_i8<4><<<(int)MC, TPB, 0, stream>>>(hf, hq + m0 * H, dqh + m0, H);
        }
    }

    // ternarize w2 into the same slot (w1q dead now)
    quant_w_i8<<<2048, TPB, 0, stream>>>(w2, wq, scales, 1, nw4);

    // GEMM2: [M x H] @ [D x H]^T -> fp32 out   (grid 8x32 = 256 blocks)
    gemm8p_i8<0><<<dim3(D / 256, (int)(M / 256)), 512, 0, stream>>>(
        hq, wq, out, D, H, dqh, scales, 1);
}

// Round 6
// 369.791 us; speedup vs baseline: 3.3774x; 1.1036x over previous
//
#include <hip/hip_runtime.h>
#include <hip/hip_bf16.h>
#include <hip/hip_fp16.h>
#include <stdint.h>

#define TPB 256
#define EPSF 1e-5f

using i32x4 = __attribute__((ext_vector_type(4))) int;

// ---------------- helpers ----------------

__device__ __forceinline__ void gload16(const void* g, void* l) {
    __builtin_amdgcn_global_load_lds(
        (__attribute__((address_space(1))) void*)g,
        (__attribute__((address_space(3))) void*)l,
        16, 0, 0);
}

__device__ __forceinline__ float wave_reduce_sum(float v) {
#pragma unroll
    for (int off = 32; off > 0; off >>= 1) v += __shfl_down(v, off, 64);
    return v;
}

__device__ __forceinline__ float wave_reduce_max(float v) {
#pragma unroll
    for (int off = 32; off > 0; off >>= 1) v = fmaxf(v, __shfl_down(v, off, 64));
    return v;
}

__device__ __forceinline__ int q8(float f, float scale, float lo, float hi) {
    return (int)fminf(fmaxf(rintf(f * scale), lo), hi);
}

// fast GELU: x * sigmoid(2*u), u = sqrt(2/pi)*(x + 0.044715 x^3)
// max |dev| vs exact erf-GELU ~1e-3, far under the int8 h-quant step (~0.028)
__device__ __forceinline__ float gelu_fast(float x) {
    float x2 = x * x;
    float u = x * (0.7978845608f + 0.0356774081f * x2);
    float e = exp2f(u * -2.8853900817779268f);   // exp(-2u)
    return x * __builtin_amdgcn_rcpf(1.0f + e);
}

// ---------------- scale reduction (deterministic two-pass) ----------------

__global__ void abssum_partial(const float* __restrict__ w, int n4,
                               float* __restrict__ part) {
    const float4* w4 = (const float4*)w;
    float acc = 0.f;
    for (int i = blockIdx.x * TPB + threadIdx.x; i < n4; i += gridDim.x * TPB) {
        float4 v = w4[i];
        acc += fabsf(v.x) + fabsf(v.y) + fabsf(v.z) + fabsf(v.w);
    }
    acc = wave_reduce_sum(acc);
    __shared__ float sh[4];
    if ((threadIdx.x & 63) == 0) sh[threadIdx.x >> 6] = acc;
    __syncthreads();
    if (threadIdx.x == 0) part[blockIdx.x] = sh[0] + sh[1] + sh[2] + sh[3];
}

__global__ void finalize_scales(const float* __restrict__ part1,
                                const float* __restrict__ part2,
                                float* __restrict__ scales, int nparts, float inv_n) {
    float a = 0.f, b = 0.f;
    for (int i = threadIdx.x; i < nparts; i += TPB) { a += part1[i]; b += part2[i]; }
    a = wave_reduce_sum(a);
    b = wave_reduce_sum(b);
    __shared__ float sa[4], sb[4];
    if ((threadIdx.x & 63) == 0) { sa[threadIdx.x >> 6] = a; sb[threadIdx.x >> 6] = b; }
    __syncthreads();
    if (threadIdx.x == 0) {
        scales[0] = fmaxf((sa[0] + sa[1] + sa[2] + sa[3]) * inv_n, EPSF);
        scales[1] = fmaxf((sb[0] + sb[1] + sb[2] + sb[3]) * inv_n, EPSF);
    }
}

// ---------------- weight ternarization -> int8 ----------------

__global__ void quant_w_i8(const float* __restrict__ w,
                           signed char* __restrict__ wq,
                           const float* __restrict__ scales, int sidx, int n4) {
    const float inv = 1.0f / scales[sidx];
    const float4* w4 = (const float4*)w;
    unsigned* oq = (unsigned*)wq;
    for (int i = blockIdx.x * TPB + threadIdx.x; i < n4; i += gridDim.x * TPB) {
        float4 v = w4[i];
        unsigned p = ((unsigned)(q8(v.x, inv, -1.f, 1.f) & 0xff)) |
                     ((unsigned)(q8(v.y, inv, -1.f, 1.f) & 0xff) << 8) |
                     ((unsigned)(q8(v.z, inv, -1.f, 1.f) & 0xff) << 16) |
                     ((unsigned)(q8(v.w, inv, -1.f, 1.f) & 0xff) << 24);
        oq[i] = p;
    }
}

// ---------------- per-row activation quant: fp32 -> int8 ----------------

template <int NF4>
__global__ void quant_x_i8(const float* __restrict__ in,
                           signed char* __restrict__ outq,
                           float* __restrict__ dq, int cols) {
    const long long row = blockIdx.x;
    const float4* r4 = (const float4*)(in + row * (long long)cols);
    float4 v[NF4];
    float mx = 0.f;
#pragma unroll
    for (int j = 0; j < NF4; ++j) {
        v[j] = r4[threadIdx.x + TPB * j];
        mx = fmaxf(mx, fmaxf(fmaxf(fabsf(v[j].x), fabsf(v[j].y)),
                             fmaxf(fabsf(v[j].z), fabsf(v[j].w))));
    }
    mx = wave_reduce_max(mx);
    __shared__ float sh[4];
    __shared__ float res;
    if ((threadIdx.x & 63) == 0) sh[threadIdx.x >> 6] = mx;
    __syncthreads();
    if (threadIdx.x == 0) res = fmaxf(fmaxf(sh[0], sh[1]), fmaxf(sh[2], sh[3]));
    __syncthreads();
    const float clipped = fmaxf(res, EPSF);
    const float scale = 127.f / clipped;
    if (threadIdx.x == 0) dq[row] = clipped / 127.f;
    unsigned* oq = (unsigned*)(outq + row * (long long)cols);
#pragma unroll
    for (int j = 0; j < NF4; ++j) {
        unsigned p = ((unsigned)(q8(v[j].x, scale, -128.f, 127.f) & 0xff)) |
                     ((unsigned)(q8(v[j].y, scale, -128.f, 127.f) & 0xff) << 8) |
                     ((unsigned)(q8(v[j].z, scale, -128.f, 127.f) & 0xff) << 16) |
                     ((unsigned)(q8(v[j].w, scale, -128.f, 127.f) & 0xff) << 24);
        oq[threadIdx.x + TPB * j] = p;
    }
}

// ---------------- per-row quant: fp16 -> int8 (for h) ----------------

template <int NJ>
__global__ void quant_h_i8(const unsigned short* __restrict__ h,
                           signed char* __restrict__ outq,
                           float* __restrict__ dq, int cols) {
    const long long row = blockIdx.x;
    const unsigned short* rp = h + row * (long long)cols;
    uint4 v[NJ];
    float mx = 0.f;
#pragma unroll
    for (int j = 0; j < NJ; ++j) {
        v[j] = *(const uint4*)(rp + (threadIdx.x + TPB * j) * 8);
        const unsigned* u = (const unsigned*)&v[j];
#pragma unroll
        for (int e = 0; e < 4; ++e) {
            float2 f2 = __half22float2(*(const __half2*)&u[e]);
            mx = fmaxf(mx, fmaxf(fabsf(f2.x), fabsf(f2.y)));
        }
    }
    mx = wave_reduce_max(mx);
    __shared__ float sh[4];
    __shared__ float res;
    if ((threadIdx.x & 63) == 0) sh[threadIdx.x >> 6] = mx;
    __syncthreads();
    if (threadIdx.x == 0) res = fmaxf(fmaxf(sh[0], sh[1]), fmaxf(sh[2], sh[3]));
    __syncthreads();
    const float clipped = fmaxf(res, EPSF);
    const float scale = 127.f / clipped;
    if (threadIdx.x == 0) dq[row] = clipped / 127.f;
    uint2* oq = (uint2*)(outq + row * (long long)cols);
#pragma unroll
    for (int j = 0; j < NJ; ++j) {
        const unsigned* u = (const unsigned*)&v[j];
        unsigned o[2] = {0, 0};
#pragma unroll
        for (int e = 0; e < 4; ++e) {
            float2 f2 = __half22float2(*(const __half2*)&u[e]);
            unsigned b0 = (unsigned)(q8(f2.x, scale, -128.f, 127.f) & 0xff);
            unsigned b1 = (unsigned)(q8(f2.y, scale, -128.f, 127.f) & 0xff);
            o[e >> 1] |= (b0 | (b1 << 8)) << ((e & 1) * 16);
        }
        oq[threadIdx.x + TPB * j] = *(uint2*)o;
    }
}

// ---------------- shared GEMM pieces ----------------

__device__ __forceinline__ void stage_half(const char* Xb, long long rowB, int prow,
                                           int tk, char* dst, int tid, int cbs) {
    const long long gc = (long long)tk * 128 + cbs;
    const int r = tid >> 3;
    gload16(Xb + (long long)(prow + r) * rowB + gc, dst + tid * 16);
    gload16(Xb + (long long)(prow + 64 + r) * rowB + gc, dst + 8192 + tid * 16);
}

#define QUAD(MB, NB)                                                            \
    _Pragma("unroll") for (int mi = 0; mi < 4; ++mi)                            \
    _Pragma("unroll") for (int ni = 0; ni < 2; ++ni)                            \
    _Pragma("unroll") for (int ks = 0; ks < 2; ++ks)                            \
        acc[(MB)*4 + mi][(NB)*2 + ni] = __builtin_amdgcn_mfma_i32_16x16x64_i8(  \
            aq[mi][ks], bq[(NB)*2 + ni][ks], acc[(MB)*4 + mi][(NB)*2 + ni], 0, 0, 0);

// ---------------- persistent GEMM1: x@w1^T -> gelu -> fp16 h ----------------
// K=2048 fixed (16 k-tiles/output-tile). Each block: fixed 256-col N band,
// `ntile` consecutive 256-row M tiles. Virtual K-step stream with +1/+2
// prefetch crossing tile boundaries (no pipeline refill between tiles).

__global__ __launch_bounds__(512, 2) void gemm1p(
    const signed char* __restrict__ A, const signed char* __restrict__ B,
    unsigned short* __restrict__ C, int N, int K,
    const float* __restrict__ dq, const float* __restrict__ scales, int ntile) {
    __shared__ __align__(16) char lds[131072];

    const int tid = threadIdx.x;
    const int lane = tid & 63;
    const int wid = tid >> 6;
    const int wr = wid >> 2;
    const int wc = wid & 3;

    const unsigned gx = gridDim.x;
    unsigned lin = blockIdx.y * gx + blockIdx.x;
    const unsigned qq = (gx * gridDim.y) >> 3;
    lin = (lin & 7) * qq + (lin >> 3);
    const unsigned bx = lin % gx;    // N band
    const unsigned byg = lin / gx;   // M group (ntile tiles)

    const int n0 = (int)bx * 256;
    const long long rb = (long long)K;  // 2048 bytes per row
    const char* Ab = (const char*)A;
    const char* Bb = (const char*)B;

    const int NTT = ntile << 4;  // total virtual k-steps

    const int cbs = (((tid & 7) ^ ((tid >> 3) & 7)) << 4);
    const int l15 = lane & 15, l4 = lane >> 4;
    const int swz = (lane & 7) << 4;
    const int acb0 = (l4 * 16) ^ swz;
    const int acb1 = (64 + l4 * 16) ^ swz;
    const int aoff = wr * 16384;
    const int boff = 32768 + (wc >> 1) * 16384 + (wc & 1) * 8192;

    i32x4 acc[8][4] = {};
    i32x4 aq[4][2], bq[4][2];

    // m-row base for virtual step v's tile
    auto mrow = [&](int v) -> int { return ((int)byg * ntile + (v >> 4)) * 256; };

    // prologue: vt=0 full into buf0, vt=1 (B0,B1,A0) into buf1
    stage_half(Bb, rb, n0, 0, lds + 32768, tid, cbs);
    stage_half(Bb, rb, n0 + 128, 0, lds + 32768 + 16384, tid, cbs);
    stage_half(Ab, rb, mrow(0), 0, lds + 0, tid, cbs);
    stage_half(Ab, rb, mrow(0) + 128, 0, lds + 16384, tid, cbs);
    stage_half(Bb, rb, n0, 1, lds + 65536 + 32768, tid, cbs);
    stage_half(Bb, rb, n0 + 128, 1, lds + 65536 + 32768 + 16384, tid, cbs);
    stage_half(Ab, rb, mrow(1), 1, lds + 65536, tid, cbs);
    asm volatile("s_waitcnt vmcnt(6)" ::: "memory");
    __builtin_amdgcn_sched_barrier(0);
    __builtin_amdgcn_s_barrier();

    const float s = scales[0];

    for (int vt = 0; vt < NTT; ++vt) {
        char* cur = lds + ((vt & 1) << 16);
        char* nxt = lds + (((vt + 1) & 1) << 16);
        const bool s1 = (vt + 1) < NTT;
        const bool s2 = (vt + 2) < NTT;
        const int k1 = (vt + 1) & 15;
        const int k2 = (vt + 2) & 15;

        // P0: read A[mh0]+B[all]; stage A1(vt+1)->nxt; MFMA q(0,0)
#pragma unroll
        for (int mi = 0; mi < 4; ++mi) {
            const char* p = cur + aoff + (mi * 16 + l15) * 128;
            aq[mi][0] = *(const i32x4*)(p + acb0);
            aq[mi][1] = *(const i32x4*)(p + acb1);
        }
#pragma unroll
        for (int ni = 0; ni < 4; ++ni) {
            const char* p = cur + boff + (ni * 16 + l15) * 128;
            bq[ni][0] = *(const i32x4*)(p + acb0);
            bq[ni][1] = *(const i32x4*)(p + acb1);
        }
        if (s1) stage_half(Ab, rb, mrow(vt + 1) + 128, k1, nxt + 16384, tid, cbs);
        __builtin_amdgcn_s_setprio(1);
        QUAD(0, 0);
        __builtin_amdgcn_s_setprio(0);
        __builtin_amdgcn_s_barrier();

        // P1: stage B0(vt+2)->cur; MFMA q(0,1)
        if (s2) stage_half(Bb, rb, n0, k2, cur + 32768, tid, cbs);
        __builtin_amdgcn_s_setprio(1);
        QUAD(0, 1);
        __builtin_amdgcn_s_setprio(0);
        __builtin_amdgcn_s_barrier();

        // P2: read A[mh1]; stage B1(vt+2)->cur; MFMA q(1,0)
#pragma unroll
        for (int mi = 0; mi < 4; ++mi) {
            const char* p = cur + aoff + ((mi + 4) * 16 + l15) * 128;
            aq[mi][0] = *(const i32x4*)(p + acb0);
            aq[mi][1] = *(const i32x4*)(p + acb1);
        }
        if (s2) stage_half(Bb, rb, n0 + 128, k2, cur + 32768 + 16384, tid, cbs);
        __builtin_amdgcn_s_setprio(1);
        QUAD(1, 0);
        __builtin_amdgcn_s_setprio(0);
        __builtin_amdgcn_s_barrier();

        // P3: stage A0(vt+2)->cur; MFMA q(1,1); counted vmcnt
        if (s2) stage_half(Ab, rb, mrow(vt + 2), k2, cur, tid, cbs);
        __builtin_amdgcn_s_setprio(1);
        QUAD(1, 1);
        __builtin_amdgcn_s_setprio(0);
        if (s2) { asm volatile("s_waitcnt vmcnt(6)" ::: "memory"); }
        else    { asm volatile("s_waitcnt vmcnt(0)" ::: "memory"); }
        __builtin_amdgcn_sched_barrier(0);
        __builtin_amdgcn_s_barrier();

        // tile finished -> epilogue (registers+global only; prefetch in flight)
        if ((vt & 15) == 15) {
            const int m0 = mrow(vt);
#pragma unroll
            for (int mi = 0; mi < 8; ++mi) {
#pragma unroll
                for (int r = 0; r < 4; ++r) {
                    const long long m = m0 + wr * 128 + mi * 16 + l4 * 4 + r;
                    const float f = dq[m] * s;
#pragma unroll
                    for (int ni = 0; ni < 4; ++ni) {
                        const long long n = n0 + wc * 64 + ni * 16 + l15;
                        float v = gelu_fast((float)acc[mi][ni][r] * f);
                        __half hh = __float2half(v);
                        C[m * (long long)N + n] = *(const unsigned short*)&hh;
                        acc[mi][ni][r] = 0;
                    }
                }
            }
        }
    }
}

// ---------------- 256x256 8-phase i8 GEMM2 (unchanged from R4/R5) ----------------

__global__ __launch_bounds__(512, 2) void gemm2k(
    const signed char* __restrict__ A, const signed char* __restrict__ B,
    float* __restrict__ C, int N, int K,
    const float* __restrict__ dq, const float* __restrict__ scales) {
    __shared__ __align__(16) char lds[131072];

    const int tid = threadIdx.x;
    const int lane = tid & 63;
    const int wid = tid >> 6;
    const int wr = wid >> 2;
    const int wc = wid & 3;

    const unsigned gx = gridDim.x;
    unsigned lin = blockIdx.y * gx + blockIdx.x;
    const unsigned qq = (gx * gridDim.y) >> 3;
    lin = (lin & 7) * qq + (lin >> 3);
    const unsigned bx = lin % gx;
    const unsigned by = lin / gx;

    const long long M0 = (long long)by * 256;
    const long long N0 = (long long)bx * 256;
    const long long rb = (long long)K;
    const char* Ab = (const char*)A + M0 * rb;
    const char* Bb = (const char*)B + N0 * rb;
    const int nt = K >> 7;

    const int cbs = (((tid & 7) ^ ((tid >> 3) & 7)) << 4);
    const int l15 = lane & 15, l4 = lane >> 4;
    const int swz = (lane & 7) << 4;
    const int acb0 = (l4 * 16) ^ swz;
    const int acb1 = (64 + l4 * 16) ^ swz;
    const int aoff = wr * 16384;
    const int boff = 32768 + (wc >> 1) * 16384 + (wc & 1) * 8192;

    i32x4 acc[8][4] = {};
    i32x4 aq[4][2], bq[4][2];

    stage_half(Bb, rb, 0,   0, lds + 32768,         tid, cbs);
    stage_half(Bb, rb, 128, 0, lds + 32768 + 16384, tid, cbs);
    stage_half(Ab, rb, 0,   0, lds + 0,             tid, cbs);
    stage_half(Ab, rb, 128, 0, lds + 16384,         tid, cbs);
    stage_half(Bb, rb, 0,   1, lds + 65536 + 32768,         tid, cbs);
    stage_half(Bb, rb, 128, 1, lds + 65536 + 32768 + 16384, tid, cbs);
    stage_half(Ab, rb, 0,   1, lds + 65536,                 tid, cbs);
    asm volatile("s_waitcnt vmcnt(6)" ::: "memory");
    __builtin_amdgcn_sched_barrier(0);
    __builtin_amdgcn_s_barrier();

    for (int t = 0; t < nt; ++t) {
        char* cur = lds + ((t & 1) << 16);
        char* nxt = lds + (((t + 1) & 1) << 16);
        const bool s1 = (t + 1) < nt;
        const bool s2 = (t + 2) < nt;

#pragma unroll
        for (int mi = 0; mi < 4; ++mi) {
            const char* p = cur + aoff + (mi * 16 + l15) * 128;
            aq[mi][0] = *(const i32x4*)(p + acb0);
            aq[mi][1] = *(const i32x4*)(p + acb1);
        }
#pragma unroll
        for (int ni = 0; ni < 4; ++ni) {
            const char* p = cur + boff + (ni * 16 + l15) * 128;
            bq[ni][0] = *(const i32x4*)(p + acb0);
            bq[ni][1] = *(const i32x4*)(p + acb1);
        }
        if (s1) stage_half(Ab, rb, 128, t + 1, nxt + 16384, tid, cbs);
        __builtin_amdgcn_s_setprio(1);
        QUAD(0, 0);
        __builtin_amdgcn_s_setprio(0);
        __builtin_amdgcn_s_barrier();

        if (s2) stage_half(Bb, rb, 0, t + 2, cur + 32768, tid, cbs);
        __builtin_amdgcn_s_setprio(1);
        QUAD(0, 1);
        __builtin_amdgcn_s_setprio(0);
        __builtin_amdgcn_s_barrier();

#pragma unroll
        for (int mi = 0; mi < 4; ++mi) {
            const char* p = cur + aoff + ((mi + 4) * 16 + l15) * 128;
            aq[mi][0] = *(const i32x4*)(p + acb0);
            aq[mi][1] = *(const i32x4*)(p + acb1);
        }
        if (s2) stage_half(Bb, rb, 128, t + 2, cur + 32768 + 16384, tid, cbs);
        __builtin_amdgcn_s_setprio(1);
        QUAD(1, 0);
        __builtin_amdgcn_s_setprio(0);
        __builtin_amdgcn_s_barrier();

        if (s2) stage_half(Ab, rb, 0, t + 2, cur, tid, cbs);
        __builtin_amdgcn_s_setprio(1);
        QUAD(1, 1);
        __builtin_amdgcn_s_setprio(0);
        if (s2) { asm volatile("s_waitcnt vmcnt(6)" ::: "memory"); }
        else    { asm volatile("s_waitcnt vmcnt(0)" ::: "memory"); }
        __builtin_amdgcn_sched_barrier(0);
        __builtin_amdgcn_s_barrier();
    }

    const float s = scales[1];
#pragma unroll
    for (int mi = 0; mi < 8; ++mi) {
#pragma unroll
        for (int r = 0; r < 4; ++r) {
            const long long m = M0 + wr * 128 + mi * 16 + l4 * 4 + r;
            const float f = dq[m] * s;
#pragma unroll
            for (int ni = 0; ni < 4; ++ni) {
                const long long n = N0 + wc * 64 + ni * 16 + l15;
                __builtin_nontemporal_store(
                    (float)acc[mi][ni][r] * f, C + m * (long long)N + n);
            }
        }
    }
}

// ---------------- launcher ----------------

extern "C" void kernel_launch(void* const* d_in, const int* in_sizes, int n_in,
                              void* d_out, int out_size, void* d_ws, size_t ws_size,
                              hipStream_t stream) {
    (void)n_in; (void)out_size;
    const float* x  = (const float*)d_in[0];
    const float* w1 = (const float*)d_in[1];
    const float* w2 = (const float*)d_in[2];
    float* out = (float*)d_out;

    const int D = 2048, H = 8192;
    const long long M = (long long)in_sizes[0] / D;  // 8192

    char* base = (char*)d_ws;
    size_t off = 0;
    auto alloc = [&](size_t bytes) -> char* {
        char* r = base + off;
        off = (off + bytes + 255) & ~(size_t)255;
        return r;
    };

    const bool fullM = ws_size >= (size_t)236 * 1024 * 1024;
    const long long MC = fullM ? M : M / 2;

    float* part1 = (float*)alloc(2048 * 4);
    float* part2 = (float*)alloc(2048 * 4);
    float* scales = (float*)alloc(256);
    float* dqx = (float*)alloc((size_t)M * 4);
    float* dqh = (float*)alloc((size_t)M * 4);
    signed char* wq = (signed char*)alloc((size_t)H * D);      // w1 then w2 overlay
    signed char* xq = (signed char*)alloc((size_t)M * D);
    signed char* hq = (signed char*)alloc((size_t)M * H);      // int8 h (full)
    unsigned short* hf = (unsigned short*)alloc((size_t)MC * H * 2);  // fp16 h

    const int nw4 = H * D / 4;
    abssum_partial<<<2048, TPB, 0, stream>>>(w1, nw4, part1);
    abssum_partial<<<2048, TPB, 0, stream>>>(w2, nw4, part2);
    finalize_scales<<<1, TPB, 0, stream>>>(part1, part2, scales, 2048,
                                           1.0f / (float)(H * D));
    quant_w_i8<<<2048, TPB, 0, stream>>>(w1, wq, scales, 0, nw4);
    quant_x_i8<2><<<(int)M, TPB, 0, stream>>>(x, xq, dqx, D);

    if (fullM) {
        // 256 blocks, 4 M-tiles each (M=8192 -> 32 bands = 8 groups x 4)
        gemm1p<<<dim3(32, 8), 512, 0, stream>>>(xq, wq, hf, H, D, dqx, scales, 4);
        quant_h_i8<4><<<(int)M, TPB, 0, stream>>>(hf, hq, dqh, H);
    } else {
        for (int g = 0; g < 2; ++g) {
            const long long m0 = g * MC;
            // 256 blocks, 2 M-tiles each (MC=4096 -> 16 bands = 8 groups x 2)
            gemm1p<<<dim3(32, 8), 512, 0, stream>>>(
                xq + m0 * D, wq, hf, H, D, dqx + m0, scales, 2);
            quant_h_i8<4><<<(int)MC, TPB, 0, stream>>>(hf, hq + m0 * H, dqh + m0, H);
        }
    }

    // ternarize w2 into the same slot (w1q dead now)
    quant_w_i8<<<2048, TPB, 0, stream>>>(w2, wq, scales, 1, nw4);

    // GEMM2: [M x H] @ [D x H]^T -> fp32 out   (grid 8x32 = 256 blocks)
    gemm2k<<<dim3(D / 256, (int)(M / 256)), 512, 0, stream>>>(
        hq, wq, out, D, H, dqh, scales);
}

// Round 7
// 358.100 us; speedup vs baseline: 3.4877x; 1.0326x over previous
//
#include <hip/hip_runtime.h>
#include <hip/hip_bf16.h>
#include <hip/hip_fp16.h>
#include <stdint.h>

#define TPB 256
#define EPSF 1e-5f

using i32x4 = __attribute__((ext_vector_type(4))) int;

// ---------------- helpers ----------------

__device__ __forceinline__ void gload16(const void* g, void* l) {
    __builtin_amdgcn_global_load_lds(
        (__attribute__((address_space(1))) void*)g,
        (__attribute__((address_space(3))) void*)l,
        16, 0, 0);
}

__device__ __forceinline__ float wave_reduce_sum(float v) {
#pragma unroll
    for (int off = 32; off > 0; off >>= 1) v += __shfl_down(v, off, 64);
    return v;
}

__device__ __forceinline__ float wave_reduce_max(float v) {
#pragma unroll
    for (int off = 32; off > 0; off >>= 1) v = fmaxf(v, __shfl_down(v, off, 64));
    return v;
}

__device__ __forceinline__ int q8(float f, float scale, float lo, float hi) {
    return (int)fminf(fmaxf(rintf(f * scale), lo), hi);
}

// fast GELU: x * sigmoid(2*u), u = sqrt(2/pi)*(x + 0.044715 x^3)
__device__ __forceinline__ float gelu_fast(float x) {
    float x2 = x * x;
    float u = x * (0.7978845608f + 0.0356774081f * x2);
    float e = exp2f(u * -2.8853900817779268f);   // exp(-2u)
    return x * __builtin_amdgcn_rcpf(1.0f + e);
}

// ---------------- scale reduction (deterministic two-pass) ----------------
// one launch handles both weights: blocks [0,2048) -> w1, [2048,4096) -> w2

__global__ void abssum2(const float* __restrict__ w1, const float* __restrict__ w2,
                        int n4, float* __restrict__ part) {
    const bool second = blockIdx.x >= 2048;
    const float4* w4 = (const float4*)(second ? w2 : w1);
    const int b = blockIdx.x & 2047;
    float acc = 0.f;
    for (int i = b * TPB + threadIdx.x; i < n4; i += 2048 * TPB) {
        float4 v = w4[i];
        acc += fabsf(v.x) + fabsf(v.y) + fabsf(v.z) + fabsf(v.w);
    }
    acc = wave_reduce_sum(acc);
    __shared__ float sh[4];
    if ((threadIdx.x & 63) == 0) sh[threadIdx.x >> 6] = acc;
    __syncthreads();
    if (threadIdx.x == 0) part[blockIdx.x] = sh[0] + sh[1] + sh[2] + sh[3];
}

__global__ void finalize_scales(const float* __restrict__ part,
                                float* __restrict__ scales, float inv_n) {
    float a = 0.f, b = 0.f;
    for (int i = threadIdx.x; i < 2048; i += TPB) { a += part[i]; b += part[i + 2048]; }
    a = wave_reduce_sum(a);
    b = wave_reduce_sum(b);
    __shared__ float sa[4], sb[4];
    if ((threadIdx.x & 63) == 0) { sa[threadIdx.x >> 6] = a; sb[threadIdx.x >> 6] = b; }
    __syncthreads();
    if (threadIdx.x == 0) {
        scales[0] = fmaxf((sa[0] + sa[1] + sa[2] + sa[3]) * inv_n, EPSF);
        scales[1] = fmaxf((sb[0] + sb[1] + sb[2] + sb[3]) * inv_n, EPSF);
    }
}

// ---------------- weight ternarization -> int8 ----------------

__global__ void quant_w_i8(const float* __restrict__ w,
                           signed char* __restrict__ wq,
                           const float* __restrict__ scales, int sidx, int n4) {
    const float inv = 1.0f / scales[sidx];
    const float4* w4 = (const float4*)w;
    unsigned* oq = (unsigned*)wq;
    for (int i = blockIdx.x * TPB + threadIdx.x; i < n4; i += gridDim.x * TPB) {
        float4 v = w4[i];
        unsigned p = ((unsigned)(q8(v.x, inv, -1.f, 1.f) & 0xff)) |
                     ((unsigned)(q8(v.y, inv, -1.f, 1.f) & 0xff) << 8) |
                     ((unsigned)(q8(v.z, inv, -1.f, 1.f) & 0xff) << 16) |
                     ((unsigned)(q8(v.w, inv, -1.f, 1.f) & 0xff) << 24);
        oq[i] = p;
    }
}

// ---------------- per-row activation quant: fp32 -> int8 ----------------

template <int NF4>
__global__ void quant_x_i8(const float* __restrict__ in,
                           signed char* __restrict__ outq,
                           float* __restrict__ dq, int cols) {
    const long long row = blockIdx.x;
    const float4* r4 = (const float4*)(in + row * (long long)cols);
    float4 v[NF4];
    float mx = 0.f;
#pragma unroll
    for (int j = 0; j < NF4; ++j) {
        v[j] = r4[threadIdx.x + TPB * j];
        mx = fmaxf(mx, fmaxf(fmaxf(fabsf(v[j].x), fabsf(v[j].y)),
                             fmaxf(fabsf(v[j].z), fabsf(v[j].w))));
    }
    mx = wave_reduce_max(mx);
    __shared__ float sh[4];
    __shared__ float res;
    if ((threadIdx.x & 63) == 0) sh[threadIdx.x >> 6] = mx;
    __syncthreads();
    if (threadIdx.x == 0) res = fmaxf(fmaxf(sh[0], sh[1]), fmaxf(sh[2], sh[3]));
    __syncthreads();
    const float clipped = fmaxf(res, EPSF);
    const float scale = 127.f / clipped;
    if (threadIdx.x == 0) dq[row] = clipped / 127.f;
    unsigned* oq = (unsigned*)(outq + row * (long long)cols);
#pragma unroll
    for (int j = 0; j < NF4; ++j) {
        unsigned p = ((unsigned)(q8(v[j].x, scale, -128.f, 127.f) & 0xff)) |
                     ((unsigned)(q8(v[j].y, scale, -128.f, 127.f) & 0xff) << 8) |
                     ((unsigned)(q8(v[j].z, scale, -128.f, 127.f) & 0xff) << 16) |
                     ((unsigned)(q8(v[j].w, scale, -128.f, 127.f) & 0xff) << 24);
        oq[threadIdx.x + TPB * j] = p;
    }
}

// ---------------- per-row quant: fp16 -> int8 (for h) ----------------

template <int NJ>
__global__ void quant_h_i8(const unsigned short* __restrict__ h,
                           signed char* __restrict__ outq,
                           float* __restrict__ dq, int cols) {
    const long long row = blockIdx.x;
    const unsigned short* rp = h + row * (long long)cols;
    uint4 v[NJ];
    float mx = 0.f;
#pragma unroll
    for (int j = 0; j < NJ; ++j) {
        v[j] = *(const uint4*)(rp + (threadIdx.x + TPB * j) * 8);
        const unsigned* u = (const unsigned*)&v[j];
#pragma unroll
        for (int e = 0; e < 4; ++e) {
            float2 f2 = __half22float2(*(const __half2*)&u[e]);
            mx = fmaxf(mx, fmaxf(fabsf(f2.x), fabsf(f2.y)));
        }
    }
    mx = wave_reduce_max(mx);
    __shared__ float sh[4];
    __shared__ float res;
    if ((threadIdx.x & 63) == 0) sh[threadIdx.x >> 6] = mx;
    __syncthreads();
    if (threadIdx.x == 0) res = fmaxf(fmaxf(sh[0], sh[1]), fmaxf(sh[2], sh[3]));
    __syncthreads();
    const float clipped = fmaxf(res, EPSF);
    const float scale = 127.f / clipped;
    if (threadIdx.x == 0) dq[row] = clipped / 127.f;
    uint2* oq = (uint2*)(outq + row * (long long)cols);
#pragma unroll
    for (int j = 0; j < NJ; ++j) {
        const unsigned* u = (const unsigned*)&v[j];
        unsigned o[2] = {0, 0};
#pragma unroll
        for (int e = 0; e < 4; ++e) {
            float2 f2 = __half22float2(*(const __half2*)&u[e]);
            unsigned b0 = (unsigned)(q8(f2.x, scale, -128.f, 127.f) & 0xff);
            unsigned b1 = (unsigned)(q8(f2.y, scale, -128.f, 127.f) & 0xff);
            o[e >> 1] |= (b0 | (b1 << 8)) << ((e & 1) * 16);
        }
        oq[threadIdx.x + TPB * j] = *(uint2*)o;
    }
}

// ---------------- shared GEMM pieces ----------------

__device__ __forceinline__ void stage_half(const char* Xb, long long rowB, int prow,
                                           int tk, char* dst, int tid, int cbs) {
    const long long gc = (long long)tk * 128 + cbs;
    const int r = tid >> 3;
    gload16(Xb + (long long)(prow + r) * rowB + gc, dst + tid * 16);
    gload16(Xb + (long long)(prow + 64 + r) * rowB + gc, dst + 8192 + tid * 16);
}

#define QUAD(MB, NB)                                                            \
    _Pragma("unroll") for (int mi = 0; mi < 4; ++mi)                            \
    _Pragma("unroll") for (int ni = 0; ni < 2; ++ni)                            \
    _Pragma("unroll") for (int ks = 0; ks < 2; ++ks)                            \
        acc[(MB)*4 + mi][(NB)*2 + ni] = __builtin_amdgcn_mfma_i32_16x16x64_i8(  \
            aq[mi][ks], bq[(NB)*2 + ni][ks], acc[(MB)*4 + mi][(NB)*2 + ni], 0, 0, 0);

// phase-balanced fragment reads: A-mh0 + B[0..1] in P0, B[2..3] in P1, A-mh1 in P2
#define READ_A(base_mi)                                                         \
    _Pragma("unroll") for (int mi = 0; mi < 4; ++mi) {                          \
        const char* p = cur + aoff + ((mi + (base_mi)) * 16 + l15) * 128;       \
        aq[mi][0] = *(const i32x4*)(p + acb0);                                  \
        aq[mi][1] = *(const i32x4*)(p + acb1);                                  \
    }
#define READ_B(n0i, n1i)                                                        \
    _Pragma("unroll") for (int ni = (n0i); ni < (n1i); ++ni) {                  \
        const char* p = cur + boff + (ni * 16 + l15) * 128;                     \
        bq[ni][0] = *(const i32x4*)(p + acb0);                                  \
        bq[ni][1] = *(const i32x4*)(p + acb1);                                  \
    }

// ---------------- persistent GEMM1: x@w1^T -> gelu -> fp16 h ----------------
// 2D XCD chunking: XCD k owns 8 N-bands x 4 M-groups (B/XCD = 4MB -> L2-reusable).

__global__ __launch_bounds__(512, 2) void gemm1p(
    const signed char* __restrict__ A, const signed char* __restrict__ B,
    unsigned short* __restrict__ C, int N, int K,
    const float* __restrict__ dq, const float* __restrict__ scales, int ntile) {
    __shared__ __align__(16) char lds[131072];

    const int tid = threadIdx.x;
    const int lane = tid & 63;
    const int wid = tid >> 6;
    const int wr = wid >> 2;
    const int wc = wid & 3;

    // grid is 32x8 = 256 blocks; hw XCD of block = orig & 7 (round-robin)
    const unsigned orig = blockIdx.y * gridDim.x + blockIdx.x;
    const unsigned xk = orig & 7, j = orig >> 3;
    const unsigned bx = (xk & 3) * 8 + (j & 7);       // N band 0..31
    const unsigned byg = (xk >> 2) * 4 + (j >> 3);    // M group 0..7

    const int n0 = (int)bx * 256;
    const long long rb = (long long)K;
    const char* Ab = (const char*)A;
    const char* Bb = (const char*)B;

    const int NTT = ntile << 4;

    const int cbs = (((tid & 7) ^ ((tid >> 3) & 7)) << 4);
    const int l15 = lane & 15, l4 = lane >> 4;
    const int swz = (lane & 7) << 4;
    const int acb0 = (l4 * 16) ^ swz;
    const int acb1 = (64 + l4 * 16) ^ swz;
    const int aoff = wr * 16384;
    const int boff = 32768 + (wc >> 1) * 16384 + (wc & 1) * 8192;

    i32x4 acc[8][4] = {};
    i32x4 aq[4][2], bq[4][2];

    auto mrow = [&](int v) -> int { return ((int)byg * ntile + (v >> 4)) * 256; };

    stage_half(Bb, rb, n0, 0, lds + 32768, tid, cbs);
    stage_half(Bb, rb, n0 + 128, 0, lds + 32768 + 16384, tid, cbs);
    stage_half(Ab, rb, mrow(0), 0, lds + 0, tid, cbs);
    stage_half(Ab, rb, mrow(0) + 128, 0, lds + 16384, tid, cbs);
    stage_half(Bb, rb, n0, 1, lds + 65536 + 32768, tid, cbs);
    stage_half(Bb, rb, n0 + 128, 1, lds + 65536 + 32768 + 16384, tid, cbs);
    stage_half(Ab, rb, mrow(1), 1, lds + 65536, tid, cbs);
    asm volatile("s_waitcnt vmcnt(6)" ::: "memory");
    __builtin_amdgcn_sched_barrier(0);
    __builtin_amdgcn_s_barrier();

    const float s = scales[0];

    for (int vt = 0; vt < NTT; ++vt) {
        char* cur = lds + ((vt & 1) << 16);
        char* nxt = lds + (((vt + 1) & 1) << 16);
        const bool s1 = (vt + 1) < NTT;
        const bool s2 = (vt + 2) < NTT;
        const int k1 = (vt + 1) & 15;
        const int k2 = (vt + 2) & 15;

        // P0: read A-mh0 + B[0..1]; stage A1(vt+1)->nxt; MFMA q(0,0)
        READ_A(0);
        READ_B(0, 2);
        if (s1) stage_half(Ab, rb, mrow(vt + 1) + 128, k1, nxt + 16384, tid, cbs);
        __builtin_amdgcn_s_setprio(1);
        QUAD(0, 0);
        __builtin_amdgcn_s_setprio(0);
        __builtin_amdgcn_s_barrier();

        // P1: read B[2..3]; stage B0(vt+2)->cur; MFMA q(0,1)
        READ_B(2, 4);
        if (s2) stage_half(Bb, rb, n0, k2, cur + 32768, tid, cbs);
        __builtin_amdgcn_s_setprio(1);
        QUAD(0, 1);
        __builtin_amdgcn_s_setprio(0);
        __builtin_amdgcn_s_barrier();

        // P2: read A-mh1; stage B1(vt+2)->cur; MFMA q(1,0)
        READ_A(4);
        if (s2) stage_half(Bb, rb, n0 + 128, k2, cur + 32768 + 16384, tid, cbs);
        __builtin_amdgcn_s_setprio(1);
        QUAD(1, 0);
        __builtin_amdgcn_s_setprio(0);
        __builtin_amdgcn_s_barrier();

        // P3: stage A0(vt+2)->cur; MFMA q(1,1); counted vmcnt
        if (s2) stage_half(Ab, rb, mrow(vt + 2), k2, cur, tid, cbs);
        __builtin_amdgcn_s_setprio(1);
        QUAD(1, 1);
        __builtin_amdgcn_s_setprio(0);
        if (s2) { asm volatile("s_waitcnt vmcnt(6)" ::: "memory"); }
        else    { asm volatile("s_waitcnt vmcnt(0)" ::: "memory"); }
        __builtin_amdgcn_sched_barrier(0);
        __builtin_amdgcn_s_barrier();

        if ((vt & 15) == 15) {
            const int m0 = mrow(vt);
#pragma unroll
            for (int mi = 0; mi < 8; ++mi) {
#pragma unroll
                for (int r = 0; r < 4; ++r) {
                    const long long m = m0 + wr * 128 + mi * 16 + l4 * 4 + r;
                    const float f = dq[m] * s;
#pragma unroll
                    for (int ni = 0; ni < 4; ++ni) {
                        const long long n = n0 + wc * 64 + ni * 16 + l15;
                        float v = gelu_fast((float)acc[mi][ni][r] * f);
                        __half hh = __float2half(v);
                        C[m * (long long)N + n] = *(const unsigned short*)&hh;
                        acc[mi][ni][r] = 0;
                    }
                }
            }
        }
    }
}

// ---------------- 256x256 8-phase i8 GEMM2 ----------------

__global__ __launch_bounds__(512, 2) void gemm2k(
    const signed char* __restrict__ A, const signed char* __restrict__ B,
    float* __restrict__ C, int N, int K,
    const float* __restrict__ dq, const float* __restrict__ scales) {
    __shared__ __align__(16) char lds[131072];

    const int tid = threadIdx.x;
    const int lane = tid & 63;
    const int wid = tid >> 6;
    const int wr = wid >> 2;
    const int wc = wid & 3;

    const unsigned gx = gridDim.x;
    unsigned lin = blockIdx.y * gx + blockIdx.x;
    const unsigned qq = (gx * gridDim.y) >> 3;
    lin = (lin & 7) * qq + (lin >> 3);
    const unsigned bx = lin % gx;
    const unsigned by = lin / gx;

    const long long M0 = (long long)by * 256;
    const long long N0 = (long long)bx * 256;
    const long long rb = (long long)K;
    const char* Ab = (const char*)A + M0 * rb;
    const char* Bb = (const char*)B + N0 * rb;
    const int nt = K >> 7;

    const int cbs = (((tid & 7) ^ ((tid >> 3) & 7)) << 4);
    const int l15 = lane & 15, l4 = lane >> 4;
    const int swz = (lane & 7) << 4;
    const int acb0 = (l4 * 16) ^ swz;
    const int acb1 = (64 + l4 * 16) ^ swz;
    const int aoff = wr * 16384;
    const int boff = 32768 + (wc >> 1) * 16384 + (wc & 1) * 8192;

    i32x4 acc[8][4] = {};
    i32x4 aq[4][2], bq[4][2];

    stage_half(Bb, rb, 0,   0, lds + 32768,         tid, cbs);
    stage_half(Bb, rb, 128, 0, lds + 32768 + 16384, tid, cbs);
    stage_half(Ab, rb, 0,   0, lds + 0,             tid, cbs);
    stage_half(Ab, rb, 128, 0, lds + 16384,         tid, cbs);
    stage_half(Bb, rb, 0,   1, lds + 65536 + 32768,         tid, cbs);
    stage_half(Bb, rb, 128, 1, lds + 65536 + 32768 + 16384, tid, cbs);
    stage_half(Ab, rb, 0,   1, lds + 65536,                 tid, cbs);
    asm volatile("s_waitcnt vmcnt(6)" ::: "memory");
    __builtin_amdgcn_sched_barrier(0);
    __builtin_amdgcn_s_barrier();

    for (int t = 0; t < nt; ++t) {
        char* cur = lds + ((t & 1) << 16);
        char* nxt = lds + (((t + 1) & 1) << 16);
        const bool s1 = (t + 1) < nt;
        const bool s2 = (t + 2) < nt;

        READ_A(0);
        READ_B(0, 2);
        if (s1) stage_half(Ab, rb, 128, t + 1, nxt + 16384, tid, cbs);
        __builtin_amdgcn_s_setprio(1);
        QUAD(0, 0);
        __builtin_amdgcn_s_setprio(0);
        __builtin_amdgcn_s_barrier();

        READ_B(2, 4);
        if (s2) stage_half(Bb, rb, 0, t + 2, cur + 32768, tid, cbs);
        __builtin_amdgcn_s_setprio(1);
        QUAD(0, 1);
        __builtin_amdgcn_s_setprio(0);
        __builtin_amdgcn_s_barrier();

        READ_A(4);
        if (s2) stage_half(Bb, rb, 128, t + 2, cur + 32768 + 16384, tid, cbs);
        __builtin_amdgcn_s_setprio(1);
        QUAD(1, 0);
        __builtin_amdgcn_s_setprio(0);
        __builtin_amdgcn_s_barrier();

        if (s2) stage_half(Ab, rb, 0, t + 2, cur, tid, cbs);
        __builtin_amdgcn_s_setprio(1);
        QUAD(1, 1);
        __builtin_amdgcn_s_setprio(0);
        if (s2) { asm volatile("s_waitcnt vmcnt(6)" ::: "memory"); }
        else    { asm volatile("s_waitcnt vmcnt(0)" ::: "memory"); }
        __builtin_amdgcn_sched_barrier(0);
        __builtin_amdgcn_s_barrier();
    }

    const float s = scales[1];
#pragma unroll
    for (int mi = 0; mi < 8; ++mi) {
#pragma unroll
        for (int r = 0; r < 4; ++r) {
            const long long m = M0 + wr * 128 + mi * 16 + l4 * 4 + r;
            const float f = dq[m] * s;
#pragma unroll
            for (int ni = 0; ni < 4; ++ni) {
                const long long n = N0 + wc * 64 + ni * 16 + l15;
                __builtin_nontemporal_store(
                    (float)acc[mi][ni][r] * f, C + m * (long long)N + n);
            }
        }
    }
}

// ---------------- launcher ----------------

extern "C" void kernel_launch(void* const* d_in, const int* in_sizes, int n_in,
                              void* d_out, int out_size, void* d_ws, size_t ws_size,
                              hipStream_t stream) {
    (void)n_in; (void)out_size;
    const float* x  = (const float*)d_in[0];
    const float* w1 = (const float*)d_in[1];
    const float* w2 = (const float*)d_in[2];
    float* out = (float*)d_out;

    const int D = 2048, H = 8192;
    const long long M = (long long)in_sizes[0] / D;  // 8192

    char* base = (char*)d_ws;
    size_t off = 0;
    auto alloc = [&](size_t bytes) -> char* {
        char* r = base + off;
        off = (off + bytes + 255) & ~(size_t)255;
        return r;
    };

    const bool fullM = ws_size >= (size_t)236 * 1024 * 1024;
    const long long MC = fullM ? M : M / 2;

    float* part = (float*)alloc(4096 * 4);
    float* scales = (float*)alloc(256);
    float* dqx = (float*)alloc((size_t)M * 4);
    float* dqh = (float*)alloc((size_t)M * 4);
    signed char* wq = (signed char*)alloc((size_t)H * D);      // w1 then w2 overlay
    signed char* xq = (signed char*)alloc((size_t)M * D);
    signed char* hq = (signed char*)alloc((size_t)M * H);      // int8 h (full)
    unsigned short* hf = (unsigned short*)alloc((size_t)MC * H * 2);  // fp16 h

    const int nw4 = H * D / 4;
    abssum2<<<4096, TPB, 0, stream>>>(w1, w2, nw4, part);
    finalize_scales<<<1, TPB, 0, stream>>>(part, scales, 1.0f / (float)(H * D));
    quant_w_i8<<<2048, TPB, 0, stream>>>(w1, wq, scales, 0, nw4);
    quant_x_i8<2><<<(int)M, TPB, 0, stream>>>(x, xq, dqx, D);

    if (fullM) {
        gemm1p<<<dim3(32, 8), 512, 0, stream>>>(xq, wq, hf, H, D, dqx, scales, 4);
        quant_h_i8<4><<<(int)M, TPB, 0, stream>>>(hf, hq, dqh, H);
    } else {
        for (int g = 0; g < 2; ++g) {
            const long long m0 = g * MC;
            gemm1p<<<dim3(32, 8), 512, 0, stream>>>(
                xq + m0 * D, wq, hf, H, D, dqx + m0, scales, 2);
            quant_h_i8<4><<<(int)MC, TPB, 0, stream>>>(hf, hq + m0 * H, dqh + m0, H);
        }
    }

    quant_w_i8<<<2048, TPB, 0, stream>>>(w2, wq, scales, 1, nw4);

    gemm2k<<<dim3(D / 256, (int)(M / 256)), 512, 0, stream>>>(
        hq, wq, out, D, H, dqh, scales);
}

// Round 8
// 357.587 us; speedup vs baseline: 3.4927x; 1.0014x over previous
//
#include <hip/hip_runtime.h>
#include <hip/hip_bf16.h>
#include <hip/hip_fp16.h>
#include <stdint.h>

#define TPB 256
#define EPSF 1e-5f

using i32x4 = __attribute__((ext_vector_type(4))) int;

// ---------------- helpers ----------------

__device__ __forceinline__ void gload16(const void* g, void* l) {
    __builtin_amdgcn_global_load_lds(
        (__attribute__((address_space(1))) void*)g,
        (__attribute__((address_space(3))) void*)l,
        16, 0, 0);
}

__device__ __forceinline__ float wave_reduce_sum(float v) {
#pragma unroll
    for (int off = 32; off > 0; off >>= 1) v += __shfl_down(v, off, 64);
    return v;
}

__device__ __forceinline__ float wave_reduce_max(float v) {
#pragma unroll
    for (int off = 32; off > 0; off >>= 1) v = fmaxf(v, __shfl_down(v, off, 64));
    return v;
}

__device__ __forceinline__ int q8(float f, float scale, float lo, float hi) {
    return (int)fminf(fmaxf(rintf(f * scale), lo), hi);
}

// fast GELU: x * sigmoid(2*u), u = sqrt(2/pi)*(x + 0.044715 x^3)
__device__ __forceinline__ float gelu_fast(float x) {
    float x2 = x * x;
    float u = x * (0.7978845608f + 0.0356774081f * x2);
    float e = exp2f(u * -2.8853900817779268f);   // exp(-2u)
    return x * __builtin_amdgcn_rcpf(1.0f + e);
}

// ---------------- scale reduction (deterministic two-pass) ----------------

__global__ void abssum2(const float* __restrict__ w1, const float* __restrict__ w2,
                        int n4, float* __restrict__ part) {
    const bool second = blockIdx.x >= 2048;
    const float4* w4 = (const float4*)(second ? w2 : w1);
    const int b = blockIdx.x & 2047;
    float acc = 0.f;
    for (int i = b * TPB + threadIdx.x; i < n4; i += 2048 * TPB) {
        float4 v = w4[i];
        acc += fabsf(v.x) + fabsf(v.y) + fabsf(v.z) + fabsf(v.w);
    }
    acc = wave_reduce_sum(acc);
    __shared__ float sh[4];
    if ((threadIdx.x & 63) == 0) sh[threadIdx.x >> 6] = acc;
    __syncthreads();
    if (threadIdx.x == 0) part[blockIdx.x] = sh[0] + sh[1] + sh[2] + sh[3];
}

__global__ void finalize_scales(const float* __restrict__ part,
                                float* __restrict__ scales, float inv_n) {
    float a = 0.f, b = 0.f;
    for (int i = threadIdx.x; i < 2048; i += TPB) { a += part[i]; b += part[i + 2048]; }
    a = wave_reduce_sum(a);
    b = wave_reduce_sum(b);
    __shared__ float sa[4], sb[4];
    if ((threadIdx.x & 63) == 0) { sa[threadIdx.x >> 6] = a; sb[threadIdx.x >> 6] = b; }
    __syncthreads();
    if (threadIdx.x == 0) {
        scales[0] = fmaxf((sa[0] + sa[1] + sa[2] + sa[3]) * inv_n, EPSF);
        scales[1] = fmaxf((sb[0] + sb[1] + sb[2] + sb[3]) * inv_n, EPSF);
    }
}

// ---------------- weight ternarization -> int8 ----------------

__global__ void quant_w_i8(const float* __restrict__ w,
                           signed char* __restrict__ wq,
                           const float* __restrict__ scales, int sidx, int n4) {
    const float inv = 1.0f / scales[sidx];
    const float4* w4 = (const float4*)w;
    unsigned* oq = (unsigned*)wq;
    for (int i = blockIdx.x * TPB + threadIdx.x; i < n4; i += gridDim.x * TPB) {
        float4 v = w4[i];
        unsigned p = ((unsigned)(q8(v.x, inv, -1.f, 1.f) & 0xff)) |
                     ((unsigned)(q8(v.y, inv, -1.f, 1.f) & 0xff) << 8) |
                     ((unsigned)(q8(v.z, inv, -1.f, 1.f) & 0xff) << 16) |
                     ((unsigned)(q8(v.w, inv, -1.f, 1.f) & 0xff) << 24);
        oq[i] = p;
    }
}

// ---------------- per-row activation quant: fp32 -> int8 ----------------

template <int NF4>
__global__ void quant_x_i8(const float* __restrict__ in,
                           signed char* __restrict__ outq,
                           float* __restrict__ dq, int cols) {
    const long long row = blockIdx.x;
    const float4* r4 = (const float4*)(in + row * (long long)cols);
    float4 v[NF4];
    float mx = 0.f;
#pragma unroll
    for (int j = 0; j < NF4; ++j) {
        v[j] = r4[threadIdx.x + TPB * j];
        mx = fmaxf(mx, fmaxf(fmaxf(fabsf(v[j].x), fabsf(v[j].y)),
                             fmaxf(fabsf(v[j].z), fabsf(v[j].w))));
    }
    mx = wave_reduce_max(mx);
    __shared__ float sh[4];
    __shared__ float res;
    if ((threadIdx.x & 63) == 0) sh[threadIdx.x >> 6] = mx;
    __syncthreads();
    if (threadIdx.x == 0) res = fmaxf(fmaxf(sh[0], sh[1]), fmaxf(sh[2], sh[3]));
    __syncthreads();
    const float clipped = fmaxf(res, EPSF);
    const float scale = 127.f / clipped;
    if (threadIdx.x == 0) dq[row] = clipped / 127.f;
    unsigned* oq = (unsigned*)(outq + row * (long long)cols);
#pragma unroll
    for (int j = 0; j < NF4; ++j) {
        unsigned p = ((unsigned)(q8(v[j].x, scale, -128.f, 127.f) & 0xff)) |
                     ((unsigned)(q8(v[j].y, scale, -128.f, 127.f) & 0xff) << 8) |
                     ((unsigned)(q8(v[j].z, scale, -128.f, 127.f) & 0xff) << 16) |
                     ((unsigned)(q8(v[j].w, scale, -128.f, 127.f) & 0xff) << 24);
        oq[threadIdx.x + TPB * j] = p;
    }
}

// ---------------- per-row quant: fp16 -> int8 (for h) ----------------

template <int NJ>
__global__ void quant_h_i8(const unsigned short* __restrict__ h,
                           signed char* __restrict__ outq,
                           float* __restrict__ dq, int cols) {
    const long long row = blockIdx.x;
    const unsigned short* rp = h + row * (long long)cols;
    uint4 v[NJ];
    float mx = 0.f;
#pragma unroll
    for (int j = 0; j < NJ; ++j) {
        v[j] = *(const uint4*)(rp + (threadIdx.x + TPB * j) * 8);
        const unsigned* u = (const unsigned*)&v[j];
#pragma unroll
        for (int e = 0; e < 4; ++e) {
            float2 f2 = __half22float2(*(const __half2*)&u[e]);
            mx = fmaxf(mx, fmaxf(fabsf(f2.x), fabsf(f2.y)));
        }
    }
    mx = wave_reduce_max(mx);
    __shared__ float sh[4];
    __shared__ float res;
    if ((threadIdx.x & 63) == 0) sh[threadIdx.x >> 6] = mx;
    __syncthreads();
    if (threadIdx.x == 0) res = fmaxf(fmaxf(sh[0], sh[1]), fmaxf(sh[2], sh[3]));
    __syncthreads();
    const float clipped = fmaxf(res, EPSF);
    const float scale = 127.f / clipped;
    if (threadIdx.x == 0) dq[row] = clipped / 127.f;
    uint2* oq = (uint2*)(outq + row * (long long)cols);
#pragma unroll
    for (int j = 0; j < NJ; ++j) {
        const unsigned* u = (const unsigned*)&v[j];
        unsigned o[2] = {0, 0};
#pragma unroll
        for (int e = 0; e < 4; ++e) {
            float2 f2 = __half22float2(*(const __half2*)&u[e]);
            unsigned b0 = (unsigned)(q8(f2.x, scale, -128.f, 127.f) & 0xff);
            unsigned b1 = (unsigned)(q8(f2.y, scale, -128.f, 127.f) & 0xff);
            o[e >> 1] |= (b0 | (b1 << 8)) << ((e & 1) * 16);
        }
        oq[threadIdx.x + TPB * j] = *(uint2*)o;
    }
}

// ---------------- shared GEMM pieces ----------------

__device__ __forceinline__ void stage_half(const char* Xb, long long rowB, int prow,
                                           int tk, char* dst, int tid, int cbs) {
    const long long gc = (long long)tk * 128 + cbs;
    const int r = tid >> 3;
    gload16(Xb + (long long)(prow + r) * rowB + gc, dst + tid * 16);
    gload16(Xb + (long long)(prow + 64 + r) * rowB + gc, dst + 8192 + tid * 16);
}

#define QUAD(MB, NB)                                                            \
    _Pragma("unroll") for (int mi = 0; mi < 4; ++mi)                            \
    _Pragma("unroll") for (int ni = 0; ni < 2; ++ni)                            \
    _Pragma("unroll") for (int ks = 0; ks < 2; ++ks)                            \
        acc[(MB)*4 + mi][(NB)*2 + ni] = __builtin_amdgcn_mfma_i32_16x16x64_i8(  \
            aq[mi][ks], bq[(NB)*2 + ni][ks], acc[(MB)*4 + mi][(NB)*2 + ni], 0, 0, 0);

#define READ_A(base_mi)                                                         \
    _Pragma("unroll") for (int mi = 0; mi < 4; ++mi) {                          \
        const char* p = cur + aoff + ((mi + (base_mi)) * 16 + l15) * 128;       \
        aq[mi][0] = *(const i32x4*)(p + acb0);                                  \
        aq[mi][1] = *(const i32x4*)(p + acb1);                                  \
    }
#define READ_B(n0i, n1i)                                                        \
    _Pragma("unroll") for (int ni = (n0i); ni < (n1i); ++ni) {                  \
        const char* p = cur + boff + (ni * 16 + l15) * 128;                     \
        bq[ni][0] = *(const i32x4*)(p + acb0);                                  \
        bq[ni][1] = *(const i32x4*)(p + acb1);                                  \
    }

// split epilogue for gemm1p: rows [MLO,MHI), gelu + fp16 store, zero acc
#define EMIT1(MLO, MHI, M0V)                                                    \
    _Pragma("unroll") for (int mi = (MLO); mi < (MHI); ++mi) {                  \
        _Pragma("unroll") for (int r = 0; r < 4; ++r) {                         \
            const long long m = (M0V) + wr * 128 + mi * 16 + l4 * 4 + r;        \
            const float f = dq[m] * s;                                          \
            _Pragma("unroll") for (int ni = 0; ni < 4; ++ni) {                  \
                const long long n = n0 + wc * 64 + ni * 16 + l15;               \
                float v = gelu_fast((float)acc[mi][ni][r] * f);                 \
                __half hh = __float2half(v);                                    \
                C[m * (long long)N + n] = *(const unsigned short*)&hh;          \
                acc[mi][ni][r] = 0;                                             \
            }                                                                   \
        }                                                                       \
    }

// ---------------- persistent GEMM1: x@w1^T -> gelu -> fp16 h ----------------
// 2D XCD chunking + split-emit epilogue (lo half at last-K P2, hi half at
// next tile's P0 — acc-quadrant hazard-free, overlaps epilogue with MFMA).

__global__ __launch_bounds__(512, 2) void gemm1p(
    const signed char* __restrict__ A, const signed char* __restrict__ B,
    unsigned short* __restrict__ C, int N, int K,
    const float* __restrict__ dq, const float* __restrict__ scales, int ntile) {
    __shared__ __align__(16) char lds[131072];

    const int tid = threadIdx.x;
    const int lane = tid & 63;
    const int wid = tid >> 6;
    const int wr = wid >> 2;
    const int wc = wid & 3;

    const unsigned orig = blockIdx.y * gridDim.x + blockIdx.x;
    const unsigned xk = orig & 7, j = orig >> 3;
    const unsigned bx = (xk & 3) * 8 + (j & 7);       // N band 0..31
    const unsigned byg = (xk >> 2) * 4 + (j >> 3);    // M group 0..7

    const int n0 = (int)bx * 256;
    const long long rb = (long long)K;
    const char* Ab = (const char*)A;
    const char* Bb = (const char*)B;

    const int NTT = ntile << 4;

    const int cbs = (((tid & 7) ^ ((tid >> 3) & 7)) << 4);
    const int l15 = lane & 15, l4 = lane >> 4;
    const int swz = (lane & 7) << 4;
    const int acb0 = (l4 * 16) ^ swz;
    const int acb1 = (64 + l4 * 16) ^ swz;
    const int aoff = wr * 16384;
    const int boff = 32768 + (wc >> 1) * 16384 + (wc & 1) * 8192;

    i32x4 acc[8][4] = {};
    i32x4 aq[4][2], bq[4][2];

    auto mrow = [&](int v) -> int { return ((int)byg * ntile + (v >> 4)) * 256; };

    stage_half(Bb, rb, n0, 0, lds + 32768, tid, cbs);
    stage_half(Bb, rb, n0 + 128, 0, lds + 32768 + 16384, tid, cbs);
    stage_half(Ab, rb, mrow(0), 0, lds + 0, tid, cbs);
    stage_half(Ab, rb, mrow(0) + 128, 0, lds + 16384, tid, cbs);
    stage_half(Bb, rb, n0, 1, lds + 65536 + 32768, tid, cbs);
    stage_half(Bb, rb, n0 + 128, 1, lds + 65536 + 32768 + 16384, tid, cbs);
    stage_half(Ab, rb, mrow(1), 1, lds + 65536, tid, cbs);
    asm volatile("s_waitcnt vmcnt(6)" ::: "memory");
    __builtin_amdgcn_sched_barrier(0);
    __builtin_amdgcn_s_barrier();

    const float s = scales[0];

    for (int vt = 0; vt < NTT; ++vt) {
        char* cur = lds + ((vt & 1) << 16);
        char* nxt = lds + (((vt + 1) & 1) << 16);
        const bool s1 = (vt + 1) < NTT;
        const bool s2 = (vt + 2) < NTT;
        const int kk = vt & 15;
        const int k1 = (vt + 1) & 15;
        const int k2 = (vt + 2) & 15;

        // P0: read A-mh0 + B[0..1]; stage A1(vt+1)->nxt; emit_hi(prev tile);
        //     MFMA q(0,0)  [emit_hi reads acc[4..7], q(0,*) writes acc[0..3]]
        READ_A(0);
        READ_B(0, 2);
        if (s1) stage_half(Ab, rb, mrow(vt + 1) + 128, k1, nxt + 16384, tid, cbs);
        if (kk == 0 && vt > 0) { EMIT1(4, 8, mrow(vt - 1)); }
        __builtin_amdgcn_s_setprio(1);
        QUAD(0, 0);
        __builtin_amdgcn_s_setprio(0);
        __builtin_amdgcn_s_barrier();

        // P1: read B[2..3]; stage B0(vt+2)->cur; MFMA q(0,1)
        READ_B(2, 4);
        if (s2) stage_half(Bb, rb, n0, k2, cur + 32768, tid, cbs);
        __builtin_amdgcn_s_setprio(1);
        QUAD(0, 1);
        __builtin_amdgcn_s_setprio(0);
        __builtin_amdgcn_s_barrier();

        // P2: read A-mh1; stage B1(vt+2)->cur; emit_lo(this tile, rows final
        //     after P1); MFMA q(1,0)  [emit_lo reads acc[0..3], q(1,*) writes 4..7]
        READ_A(4);
        if (s2) stage_half(Bb, rb, n0 + 128, k2, cur + 32768 + 16384, tid, cbs);
        if (kk == 15) { EMIT1(0, 4, mrow(vt)); }
        __builtin_amdgcn_s_setprio(1);
        QUAD(1, 0);
        __builtin_amdgcn_s_setprio(0);
        __builtin_amdgcn_s_barrier();

        // P3: stage A0(vt+2)->cur; MFMA q(1,1); counted vmcnt
        if (s2) stage_half(Ab, rb, mrow(vt + 2), k2, cur, tid, cbs);
        __builtin_amdgcn_s_setprio(1);
        QUAD(1, 1);
        __builtin_amdgcn_s_setprio(0);
        if (s2) { asm volatile("s_waitcnt vmcnt(6)" ::: "memory"); }
        else    { asm volatile("s_waitcnt vmcnt(0)" ::: "memory"); }
        __builtin_amdgcn_sched_barrier(0);
        __builtin_amdgcn_s_barrier();
    }

    // tail: hi half of the last tile
    { EMIT1(4, 8, mrow(NTT - 1)); }
}

// ---------------- 256x256 8-phase i8 GEMM2 ----------------

#define EMIT2(MLO, MHI)                                                         \
    _Pragma("unroll") for (int mi = (MLO); mi < (MHI); ++mi) {                  \
        _Pragma("unroll") for (int r = 0; r < 4; ++r) {                         \
            const long long m = M0 + wr * 128 + mi * 16 + l4 * 4 + r;           \
            const float f = dq[m] * s;                                          \
            _Pragma("unroll") for (int ni = 0; ni < 4; ++ni) {                  \
                const long long n = N0 + wc * 64 + ni * 16 + l15;               \
                __builtin_nontemporal_store(                                    \
                    (float)acc[mi][ni][r] * f, C + m * (long long)N + n);       \
            }                                                                   \
        }                                                                       \
    }

__global__ __launch_bounds__(512, 2) void gemm2k(
    const signed char* __restrict__ A, const signed char* __restrict__ B,
    float* __restrict__ C, int N, int K,
    const float* __restrict__ dq, const float* __restrict__ scales) {
    __shared__ __align__(16) char lds[131072];

    const int tid = threadIdx.x;
    const int lane = tid & 63;
    const int wid = tid >> 6;
    const int wr = wid >> 2;
    const int wc = wid & 3;

    const unsigned gx = gridDim.x;
    unsigned lin = blockIdx.y * gx + blockIdx.x;
    const unsigned qq = (gx * gridDim.y) >> 3;
    lin = (lin & 7) * qq + (lin >> 3);
    const unsigned bx = lin % gx;
    const unsigned by = lin / gx;

    const long long M0 = (long long)by * 256;
    const long long N0 = (long long)bx * 256;
    const long long rb = (long long)K;
    const char* Ab = (const char*)A + M0 * rb;
    const char* Bb = (const char*)B + N0 * rb;
    const int nt = K >> 7;

    const int cbs = (((tid & 7) ^ ((tid >> 3) & 7)) << 4);
    const int l15 = lane & 15, l4 = lane >> 4;
    const int swz = (lane & 7) << 4;
    const int acb0 = (l4 * 16) ^ swz;
    const int acb1 = (64 + l4 * 16) ^ swz;
    const int aoff = wr * 16384;
    const int boff = 32768 + (wc >> 1) * 16384 + (wc & 1) * 8192;

    i32x4 acc[8][4] = {};
    i32x4 aq[4][2], bq[4][2];

    stage_half(Bb, rb, 0,   0, lds + 32768,         tid, cbs);
    stage_half(Bb, rb, 128, 0, lds + 32768 + 16384, tid, cbs);
    stage_half(Ab, rb, 0,   0, lds + 0,             tid, cbs);
    stage_half(Ab, rb, 128, 0, lds + 16384,         tid, cbs);
    stage_half(Bb, rb, 0,   1, lds + 65536 + 32768,         tid, cbs);
    stage_half(Bb, rb, 128, 1, lds + 65536 + 32768 + 16384, tid, cbs);
    stage_half(Ab, rb, 0,   1, lds + 65536,                 tid, cbs);
    asm volatile("s_waitcnt vmcnt(6)" ::: "memory");
    __builtin_amdgcn_sched_barrier(0);
    __builtin_amdgcn_s_barrier();

    const float s = scales[1];

    for (int t = 0; t < nt; ++t) {
        char* cur = lds + ((t & 1) << 16);
        char* nxt = lds + (((t + 1) & 1) << 16);
        const bool s1 = (t + 1) < nt;
        const bool s2 = (t + 2) < nt;

        READ_A(0);
        READ_B(0, 2);
        if (s1) stage_half(Ab, rb, 128, t + 1, nxt + 16384, tid, cbs);
        __builtin_amdgcn_s_setprio(1);
        QUAD(0, 0);
        __builtin_amdgcn_s_setprio(0);
        __builtin_amdgcn_s_barrier();

        READ_B(2, 4);
        if (s2) stage_half(Bb, rb, 0, t + 2, cur + 32768, tid, cbs);
        __builtin_amdgcn_s_setprio(1);
        QUAD(0, 1);
        __builtin_amdgcn_s_setprio(0);
        __builtin_amdgcn_s_barrier();

        READ_A(4);
        if (s2) stage_half(Bb, rb, 128, t + 2, cur + 32768 + 16384, tid, cbs);
        if (t == nt - 1) { EMIT2(0, 4); }   // rows 0..3 final after P1
        __builtin_amdgcn_s_setprio(1);
        QUAD(1, 0);
        __builtin_amdgcn_s_setprio(0);
        __builtin_amdgcn_s_barrier();

        if (s2) stage_half(Ab, rb, 0, t + 2, cur, tid, cbs);
        __builtin_amdgcn_s_setprio(1);
        QUAD(1, 1);
        __builtin_amdgcn_s_setprio(0);
        if (s2) { asm volatile("s_waitcnt vmcnt(6)" ::: "memory"); }
        else    { asm volatile("s_waitcnt vmcnt(0)" ::: "memory"); }
        __builtin_amdgcn_sched_barrier(0);
        __builtin_amdgcn_s_barrier();
    }

    { EMIT2(4, 8); }
}

// ---------------- launcher ----------------

extern "C" void kernel_launch(void* const* d_in, const int* in_sizes, int n_in,
                              void* d_out, int out_size, void* d_ws, size_t ws_size,
                              hipStream_t stream) {
    (void)n_in; (void)out_size;
    const float* x  = (const float*)d_in[0];
    const float* w1 = (const float*)d_in[1];
    const float* w2 = (const float*)d_in[2];
    float* out = (float*)d_out;

    const int D = 2048, H = 8192;
    const long long M = (long long)in_sizes[0] / D;  // 8192

    char* base = (char*)d_ws;
    size_t off = 0;
    auto alloc = [&](size_t bytes) -> char* {
        char* r = base + off;
        off = (off + bytes + 255) & ~(size_t)255;
        return r;
    };

    const bool fullM = ws_size >= (size_t)236 * 1024 * 1024;
    const long long MC = fullM ? M : M / 2;

    float* part = (float*)alloc(4096 * 4);
    float* scales = (float*)alloc(256);
    float* dqx = (float*)alloc((size_t)M * 4);
    float* dqh = (float*)alloc((size_t)M * 4);
    signed char* wq = (signed char*)alloc((size_t)H * D);      // w1 then w2 overlay
    signed char* xq = (signed char*)alloc((size_t)M * D);
    signed char* hq = (signed char*)alloc((size_t)M * H);      // int8 h (full)
    unsigned short* hf = (unsigned short*)alloc((size_t)MC * H * 2);  // fp16 h

    const int nw4 = H * D / 4;
    abssum2<<<4096, TPB, 0, stream>>>(w1, w2, nw4, part);
    finalize_scales<<<1, TPB, 0, stream>>>(part, scales, 1.0f / (float)(H * D));
    quant_w_i8<<<2048, TPB, 0, stream>>>(w1, wq, scales, 0, nw4);
    quant_x_i8<2><<<(int)M, TPB, 0, stream>>>(x, xq, dqx, D);

    if (fullM) {
        gemm1p<<<dim3(32, 8), 512, 0, stream>>>(xq, wq, hf, H, D, dqx, scales, 4);
        quant_h_i8<4><<<(int)M, TPB, 0, stream>>>(hf, hq, dqh, H);
    } else {
        for (int g = 0; g < 2; ++g) {
            const long long m0 = g * MC;
            gemm1p<<<dim3(32, 8), 512, 0, stream>>>(
                xq + m0 * D, wq, hf, H, D, dqx + m0, scales, 2);
            quant_h_i8<4><<<(int)MC, TPB, 0, stream>>>(hf, hq + m0 * H, dqh + m0, H);
        }
    }

    quant_w_i8<<<2048, TPB, 0, stream>>>(w2, wq, scales, 1, nw4);

    gemm2k<<<dim3(D / 256, (int)(M / 256)), 512, 0, stream>>>(
        hq, wq, out, D, H, dqh, scales);
}

// Round 9
// 357.572 us; speedup vs baseline: 3.4928x; 1.0000x over previous
//
#include <hip/hip_runtime.h>
#include <hip/hip_bf16.h>
#include <hip/hip_fp16.h>
#include <stdint.h>

#define TPB 256
#define EPSF 1e-5f

using i32x4 = __attribute__((ext_vector_type(4))) int;

// ---------------- helpers ----------------

__device__ __forceinline__ void gload16(const void* g, void* l) {
    __builtin_amdgcn_global_load_lds(
        (__attribute__((address_space(1))) void*)g,
        (__attribute__((address_space(3))) void*)l,
        16, 0, 0);
}

__device__ __forceinline__ float wave_reduce_sum(float v) {
#pragma unroll
    for (int off = 32; off > 0; off >>= 1) v += __shfl_down(v, off, 64);
    return v;
}

__device__ __forceinline__ float wave_reduce_max(float v) {
#pragma unroll
    for (int off = 32; off > 0; off >>= 1) v = fmaxf(v, __shfl_down(v, off, 64));
    return v;
}

__device__ __forceinline__ int q8(float f, float scale, float lo, float hi) {
    return (int)fminf(fmaxf(rintf(f * scale), lo), hi);
}

// fast GELU: x * sigmoid(2*u), u = sqrt(2/pi)*(x + 0.044715 x^3)
__device__ __forceinline__ float gelu_fast(float x) {
    float x2 = x * x;
    float u = x * (0.7978845608f + 0.0356774081f * x2);
    float e = exp2f(u * -2.8853900817779268f);   // exp(-2u)
    return x * __builtin_amdgcn_rcpf(1.0f + e);
}

// ---------------- scale reduction (deterministic two-pass) ----------------

__global__ void abssum2(const float* __restrict__ w1, const float* __restrict__ w2,
                        int n4, float* __restrict__ part) {
    const bool second = blockIdx.x >= 2048;
    const float4* w4 = (const float4*)(second ? w2 : w1);
    const int b = blockIdx.x & 2047;
    float acc = 0.f;
    for (int i = b * TPB + threadIdx.x; i < n4; i += 2048 * TPB) {
        float4 v = w4[i];
        acc += fabsf(v.x) + fabsf(v.y) + fabsf(v.z) + fabsf(v.w);
    }
    acc = wave_reduce_sum(acc);
    __shared__ float sh[4];
    if ((threadIdx.x & 63) == 0) sh[threadIdx.x >> 6] = acc;
    __syncthreads();
    if (threadIdx.x == 0) part[blockIdx.x] = sh[0] + sh[1] + sh[2] + sh[3];
}

__global__ void finalize_scales(const float* __restrict__ part,
                                float* __restrict__ scales, float inv_n) {
    float a = 0.f, b = 0.f;
    for (int i = threadIdx.x; i < 2048; i += TPB) { a += part[i]; b += part[i + 2048]; }
    a = wave_reduce_sum(a);
    b = wave_reduce_sum(b);
    __shared__ float sa[4], sb[4];
    if ((threadIdx.x & 63) == 0) { sa[threadIdx.x >> 6] = a; sb[threadIdx.x >> 6] = b; }
    __syncthreads();
    if (threadIdx.x == 0) {
        scales[0] = fmaxf((sa[0] + sa[1] + sa[2] + sa[3]) * inv_n, EPSF);
        scales[1] = fmaxf((sb[0] + sb[1] + sb[2] + sb[3]) * inv_n, EPSF);
    }
}

// ---------------- weight ternarization -> int8 ----------------

__global__ void quant_w_i8(const float* __restrict__ w,
                           signed char* __restrict__ wq,
                           const float* __restrict__ scales, int sidx, int n4) {
    const float inv = 1.0f / scales[sidx];
    const float4* w4 = (const float4*)w;
    unsigned* oq = (unsigned*)wq;
    for (int i = blockIdx.x * TPB + threadIdx.x; i < n4; i += gridDim.x * TPB) {
        float4 v = w4[i];
        unsigned p = ((unsigned)(q8(v.x, inv, -1.f, 1.f) & 0xff)) |
                     ((unsigned)(q8(v.y, inv, -1.f, 1.f) & 0xff) << 8) |
                     ((unsigned)(q8(v.z, inv, -1.f, 1.f) & 0xff) << 16) |
                     ((unsigned)(q8(v.w, inv, -1.f, 1.f) & 0xff) << 24);
        oq[i] = p;
    }
}

// ---------------- per-row activation quant: fp32 -> int8 ----------------

template <int NF4>
__global__ void quant_x_i8(const float* __restrict__ in,
                           signed char* __restrict__ outq,
                           float* __restrict__ dq, int cols) {
    const long long row = blockIdx.x;
    const float4* r4 = (const float4*)(in + row * (long long)cols);
    float4 v[NF4];
    float mx = 0.f;
#pragma unroll
    for (int j = 0; j < NF4; ++j) {
        v[j] = r4[threadIdx.x + TPB * j];
        mx = fmaxf(mx, fmaxf(fmaxf(fabsf(v[j].x), fabsf(v[j].y)),
                             fmaxf(fabsf(v[j].z), fabsf(v[j].w))));
    }
    mx = wave_reduce_max(mx);
    __shared__ float sh[4];
    __shared__ float res;
    if ((threadIdx.x & 63) == 0) sh[threadIdx.x >> 6] = mx;
    __syncthreads();
    if (threadIdx.x == 0) res = fmaxf(fmaxf(sh[0], sh[1]), fmaxf(sh[2], sh[3]));
    __syncthreads();
    const float clipped = fmaxf(res, EPSF);
    const float scale = 127.f / clipped;
    if (threadIdx.x == 0) dq[row] = clipped / 127.f;
    unsigned* oq = (unsigned*)(outq + row * (long long)cols);
#pragma unroll
    for (int j = 0; j < NF4; ++j) {
        unsigned p = ((unsigned)(q8(v[j].x, scale, -128.f, 127.f) & 0xff)) |
                     ((unsigned)(q8(v[j].y, scale, -128.f, 127.f) & 0xff) << 8) |
                     ((unsigned)(q8(v[j].z, scale, -128.f, 127.f) & 0xff) << 16) |
                     ((unsigned)(q8(v[j].w, scale, -128.f, 127.f) & 0xff) << 24);
        oq[threadIdx.x + TPB * j] = p;
    }
}

// ---------------- per-row quant: fp16 -> int8 (for h) ----------------

template <int NJ>
__global__ void quant_h_i8(const unsigned short* __restrict__ h,
                           signed char* __restrict__ outq,
                           float* __restrict__ dq, int cols) {
    const long long row = blockIdx.x;
    const unsigned short* rp = h + row * (long long)cols;
    uint4 v[NJ];
    float mx = 0.f;
#pragma unroll
    for (int j = 0; j < NJ; ++j) {
        v[j] = *(const uint4*)(rp + (threadIdx.x + TPB * j) * 8);
        const unsigned* u = (const unsigned*)&v[j];
#pragma unroll
        for (int e = 0; e < 4; ++e) {
            float2 f2 = __half22float2(*(const __half2*)&u[e]);
            mx = fmaxf(mx, fmaxf(fabsf(f2.x), fabsf(f2.y)));
        }
    }
    mx = wave_reduce_max(mx);
    __shared__ float sh[4];
    __shared__ float res;
    if ((threadIdx.x & 63) == 0) sh[threadIdx.x >> 6] = mx;
    __syncthreads();
    if (threadIdx.x == 0) res = fmaxf(fmaxf(sh[0], sh[1]), fmaxf(sh[2], sh[3]));
    __syncthreads();
    const float clipped = fmaxf(res, EPSF);
    const float scale = 127.f / clipped;
    if (threadIdx.x == 0) dq[row] = clipped / 127.f;
    uint2* oq = (uint2*)(outq + row * (long long)cols);
#pragma unroll
    for (int j = 0; j < NJ; ++j) {
        const unsigned* u = (const unsigned*)&v[j];
        unsigned o[2] = {0, 0};
#pragma unroll
        for (int e = 0; e < 4; ++e) {
            float2 f2 = __half22float2(*(const __half2*)&u[e]);
            unsigned b0 = (unsigned)(q8(f2.x, scale, -128.f, 127.f) & 0xff);
            unsigned b1 = (unsigned)(q8(f2.y, scale, -128.f, 127.f) & 0xff);
            o[e >> 1] |= (b0 | (b1 << 8)) << ((e & 1) * 16);
        }
        oq[threadIdx.x + TPB * j] = *(uint2*)o;
    }
}

// ---------------- shared GEMM pieces ----------------

__device__ __forceinline__ void stage_half(const char* Xb, long long rowB, int prow,
                                           int tk, char* dst, int tid, int cbs) {
    const long long gc = (long long)tk * 128 + cbs;
    const int r = tid >> 3;
    gload16(Xb + (long long)(prow + r) * rowB + gc, dst + tid * 16);
    gload16(Xb + (long long)(prow + 64 + r) * rowB + gc, dst + 8192 + tid * 16);
}

#define QUAD(MB, NB)                                                            \
    _Pragma("unroll") for (int mi = 0; mi < 4; ++mi)                            \
    _Pragma("unroll") for (int ni = 0; ni < 2; ++ni)                            \
    _Pragma("unroll") for (int ks = 0; ks < 2; ++ks)                            \
        acc[(MB)*4 + mi][(NB)*2 + ni] = __builtin_amdgcn_mfma_i32_16x16x64_i8(  \
            aq[mi][ks], bq[(NB)*2 + ni][ks], acc[(MB)*4 + mi][(NB)*2 + ni], 0, 0, 0);

// fragment reads from buffer BUF (read-ahead skeleton)
#define READ_A(BUF, base_mi)                                                    \
    _Pragma("unroll") for (int mi = 0; mi < 4; ++mi) {                          \
        const char* p = (BUF) + aoff + ((mi + (base_mi)) * 16 + l15) * 128;     \
        aq[mi][0] = *(const i32x4*)(p + acb0);                                  \
        aq[mi][1] = *(const i32x4*)(p + acb1);                                  \
    }
#define READ_B(BUF, n0i, n1i)                                                   \
    _Pragma("unroll") for (int ni = (n0i); ni < (n1i); ++ni) {                  \
        const char* p = (BUF) + boff + (ni * 16 + l15) * 128;                   \
        bq[ni][0] = *(const i32x4*)(p + acb0);                                  \
        bq[ni][1] = *(const i32x4*)(p + acb1);                                  \
    }

#define LGKM(N) do { asm volatile("s_waitcnt lgkmcnt(" #N ")" ::: "memory");    \
                     __builtin_amdgcn_sched_barrier(0); } while (0)

// split epilogue for gemm1p: rows [MLO,MHI), gelu + fp16 store, zero acc
#define EMIT1(MLO, MHI, M0V)                                                    \
    _Pragma("unroll") for (int mi = (MLO); mi < (MHI); ++mi) {                  \
        _Pragma("unroll") for (int r = 0; r < 4; ++r) {                         \
            const long long m = (M0V) + wr * 128 + mi * 16 + l4 * 4 + r;        \
            const float f = dq[m] * s;                                          \
            _Pragma("unroll") for (int ni = 0; ni < 4; ++ni) {                  \
                const long long n = n0 + wc * 64 + ni * 16 + l15;               \
                float v = gelu_fast((float)acc[mi][ni][r] * f);                 \
                __half hh = __float2half(v);                                    \
                C[m * (long long)N + n] = *(const unsigned short*)&hh;          \
                acc[mi][ni][r] = 0;                                             \
            }                                                                   \
        }                                                                       \
    }

// ---------------- persistent GEMM1: x@w1^T -> gelu -> fp16 h ----------------
// Read-ahead skeleton: every fragment read is issued >=1 barrier before its
// consuming QUAD. Staging: P0 A1(t+1)->nxt, P2 B0+B1(t+2)->cur,
// P3(post-barrier) A0(t+2)->cur. vmcnt(4) steady (12 outstanding, retire 8).

__global__ __launch_bounds__(512, 2) void gemm1p(
    const signed char* __restrict__ A, const signed char* __restrict__ B,
    unsigned short* __restrict__ C, int N, int K,
    const float* __restrict__ dq, const float* __restrict__ scales, int ntile) {
    __shared__ __align__(16) char lds[131072];

    const int tid = threadIdx.x;
    const int lane = tid & 63;
    const int wid = tid >> 6;
    const int wr = wid >> 2;
    const int wc = wid & 3;

    const unsigned orig = blockIdx.y * gridDim.x + blockIdx.x;
    const unsigned xk = orig & 7, j = orig >> 3;
    const unsigned bx = (xk & 3) * 8 + (j & 7);       // N band 0..31
    const unsigned byg = (xk >> 2) * 4 + (j >> 3);    // M group 0..7

    const int n0 = (int)bx * 256;
    const long long rb = (long long)K;
    const char* Ab = (const char*)A;
    const char* Bb = (const char*)B;

    const int NTT = ntile << 4;

    const int cbs = (((tid & 7) ^ ((tid >> 3) & 7)) << 4);
    const int l15 = lane & 15, l4 = lane >> 4;
    const int swz = (lane & 7) << 4;
    const int acb0 = (l4 * 16) ^ swz;
    const int acb1 = (64 + l4 * 16) ^ swz;
    const int aoff = wr * 16384;
    const int boff = 32768 + (wc >> 1) * 16384 + (wc & 1) * 8192;

    i32x4 acc[8][4] = {};
    i32x4 aq[4][2], bq[4][2];

    auto mrow = [&](int v) -> int { return ((int)byg * ntile + (v >> 4)) * 256; };

    // prologue: buf0 {B0,B1,A0,A1}, buf1 {B0,B1,A0}; vmcnt(6) retires buf0
    stage_half(Bb, rb, n0, 0, lds + 32768, tid, cbs);
    stage_half(Bb, rb, n0 + 128, 0, lds + 32768 + 16384, tid, cbs);
    stage_half(Ab, rb, mrow(0), 0, lds + 0, tid, cbs);
    stage_half(Ab, rb, mrow(0) + 128, 0, lds + 16384, tid, cbs);
    stage_half(Bb, rb, n0, 1, lds + 65536 + 32768, tid, cbs);
    stage_half(Bb, rb, n0 + 128, 1, lds + 65536 + 32768 + 16384, tid, cbs);
    stage_half(Ab, rb, mrow(1), 1, lds + 65536, tid, cbs);
    asm volatile("s_waitcnt vmcnt(6)" ::: "memory");
    __builtin_amdgcn_sched_barrier(0);
    __builtin_amdgcn_s_barrier();
    READ_A(lds, 0);        // mh0 of tile chunk 0
    READ_B(lds, 0, 2);     // B[0..1]

    const float s = scales[0];

    for (int vt = 0; vt < NTT; ++vt) {
        char* cur = lds + ((vt & 1) << 16);
        char* nxt = lds + (((vt + 1) & 1) << 16);
        const bool s1 = (vt + 1) < NTT;
        const bool s2 = (vt + 2) < NTT;
        const int kk = vt & 15;
        const int k1 = (vt + 1) & 15;
        const int k2 = (vt + 2) & 15;

        // P0: stage A1(vt+1)->nxt; read bqB=cur B[2..3]; emit_hi(prev tile)
        if (s1) stage_half(Ab, rb, mrow(vt + 1) + 128, k1, nxt + 16384, tid, cbs);
        READ_B(cur, 2, 4);
        if (kk == 0 && vt > 0) { EMIT1(4, 8, mrow(vt - 1)); }
        __builtin_amdgcn_s_barrier();
        LGKM(4);   // drain aq(mh0)+bqA (prev P3); leave bqB in flight
        __builtin_amdgcn_s_setprio(1);
        QUAD(0, 0);
        __builtin_amdgcn_s_setprio(0);

        // P1: spacer barrier (orders bqA/bqB drains vs P2 B-stages)
        __builtin_amdgcn_s_barrier();
        LGKM(0);   // bqB (latency hidden by P0 QUAD + barrier)
        __builtin_amdgcn_s_setprio(1);
        QUAD(0, 1);
        __builtin_amdgcn_s_setprio(0);

        // P2: stage B0+B1(vt+2)->cur; read aq=cur A-mh1; emit_lo(this tile)
        if (s2) {
            stage_half(Bb, rb, n0, k2, cur + 32768, tid, cbs);
            stage_half(Bb, rb, n0 + 128, k2, cur + 32768 + 16384, tid, cbs);
        }
        READ_A(cur, 4);
        if (kk == 15) { EMIT1(0, 4, mrow(vt)); }
        __builtin_amdgcn_s_barrier();
        LGKM(0);   // aq(mh1)
        __builtin_amdgcn_s_setprio(1);
        QUAD(1, 0);
        __builtin_amdgcn_s_setprio(0);

        // P3: vmcnt; barrier; stage A0(vt+2)->cur; QUAD(1,1); read-ahead nxt
        if (s2) { asm volatile("s_waitcnt vmcnt(4)" ::: "memory"); }
        else    { asm volatile("s_waitcnt vmcnt(0)" ::: "memory"); }
        __builtin_amdgcn_sched_barrier(0);
        __builtin_amdgcn_s_barrier();
        if (s2) stage_half(Ab, rb, mrow(vt + 2), k2, cur, tid, cbs);
        __builtin_amdgcn_s_setprio(1);
        QUAD(1, 1);
        __builtin_amdgcn_s_setprio(0);
        if (s1) {
            READ_A(nxt, 0);      // next step mh0 (WAR on aq after QUAD(1,1))
            READ_B(nxt, 0, 2);   // next step B[0..1]
        }
    }

    // tail: hi half of the last tile
    { EMIT1(4, 8, mrow(NTT - 1)); }
}

// ---------------- 256x256 read-ahead i8 GEMM2 ----------------

#define EMIT2(MLO, MHI)                                                         \
    _Pragma("unroll") for (int mi = (MLO); mi < (MHI); ++mi) {                  \
        _Pragma("unroll") for (int r = 0; r < 4; ++r) {                         \
            const long long m = M0 + wr * 128 + mi * 16 + l4 * 4 + r;           \
            const float f = dq[m] * s;                                          \
            _Pragma("unroll") for (int ni = 0; ni < 4; ++ni) {                  \
                const long long n = N0 + wc * 64 + ni * 16 + l15;               \
                __builtin_nontemporal_store(                                    \
                    (float)acc[mi][ni][r] * f, C + m * (long long)N + n);       \
            }                                                                   \
        }                                                                       \
    }

__global__ __launch_bounds__(512, 2) void gemm2k(
    const signed char* __restrict__ A, const signed char* __restrict__ B,
    float* __restrict__ C, int N, int K,
    const float* __restrict__ dq, const float* __restrict__ scales) {
    __shared__ __align__(16) char lds[131072];

    const int tid = threadIdx.x;
    const int lane = tid & 63;
    const int wid = tid >> 6;
    const int wr = wid >> 2;
    const int wc = wid & 3;

    const unsigned gx = gridDim.x;
    unsigned lin = blockIdx.y * gx + blockIdx.x;
    const unsigned qq = (gx * gridDim.y) >> 3;
    lin = (lin & 7) * qq + (lin >> 3);
    const unsigned bx = lin % gx;
    const unsigned by = lin / gx;

    const long long M0 = (long long)by * 256;
    const long long N0 = (long long)bx * 256;
    const long long rb = (long long)K;
    const char* Ab = (const char*)A + M0 * rb;
    const char* Bb = (const char*)B + N0 * rb;
    const int nt = K >> 7;

    const int cbs = (((tid & 7) ^ ((tid >> 3) & 7)) << 4);
    const int l15 = lane & 15, l4 = lane >> 4;
    const int swz = (lane & 7) << 4;
    const int acb0 = (l4 * 16) ^ swz;
    const int acb1 = (64 + l4 * 16) ^ swz;
    const int aoff = wr * 16384;
    const int boff = 32768 + (wc >> 1) * 16384 + (wc & 1) * 8192;

    i32x4 acc[8][4] = {};
    i32x4 aq[4][2], bq[4][2];

    stage_half(Bb, rb, 0,   0, lds + 32768,         tid, cbs);
    stage_half(Bb, rb, 128, 0, lds + 32768 + 16384, tid, cbs);
    stage_half(Ab, rb, 0,   0, lds + 0,             tid, cbs);
    stage_half(Ab, rb, 128, 0, lds + 16384,         tid, cbs);
    stage_half(Bb, rb, 0,   1, lds + 65536 + 32768,         tid, cbs);
    stage_half(Bb, rb, 128, 1, lds + 65536 + 32768 + 16384, tid, cbs);
    stage_half(Ab, rb, 0,   1, lds + 65536,                 tid, cbs);
    asm volatile("s_waitcnt vmcnt(6)" ::: "memory");
    __builtin_amdgcn_sched_barrier(0);
    __builtin_amdgcn_s_barrier();
    READ_A(lds, 0);
    READ_B(lds, 0, 2);

    const float s = scales[1];

    for (int t = 0; t < nt; ++t) {
        char* cur = lds + ((t & 1) << 16);
        char* nxt = lds + (((t + 1) & 1) << 16);
        const bool s1 = (t + 1) < nt;
        const bool s2 = (t + 2) < nt;

        // P0
        if (s1) stage_half(Ab, rb, 128, t + 1, nxt + 16384, tid, cbs);
        READ_B(cur, 2, 4);
        __builtin_amdgcn_s_barrier();
        LGKM(4);
        __builtin_amdgcn_s_setprio(1);
        QUAD(0, 0);
        __builtin_amdgcn_s_setprio(0);

        // P1
        __builtin_amdgcn_s_barrier();
        LGKM(0);
        __builtin_amdgcn_s_setprio(1);
        QUAD(0, 1);
        __builtin_amdgcn_s_setprio(0);

        // P2
        if (s2) {
            stage_half(Bb, rb, 0, t + 2, cur + 32768, tid, cbs);
            stage_half(Bb, rb, 128, t + 2, cur + 32768 + 16384, tid, cbs);
        }
        READ_A(cur, 4);
        if (t == nt - 1) { EMIT2(0, 4); }
        __builtin_amdgcn_s_barrier();
        LGKM(0);
        __builtin_amdgcn_s_setprio(1);
        QUAD(1, 0);
        __builtin_amdgcn_s_setprio(0);

        // P3
        if (s2) { asm volatile("s_waitcnt vmcnt(4)" ::: "memory"); }
        else    { asm volatile("s_waitcnt vmcnt(0)" ::: "memory"); }
        __builtin_amdgcn_sched_barrier(0);
        __builtin_amdgcn_s_barrier();
        if (s2) stage_half(Ab, rb, 0, t + 2, cur, tid, cbs);
        __builtin_amdgcn_s_setprio(1);
        QUAD(1, 1);
        __builtin_amdgcn_s_setprio(0);
        if (s1) {
            READ_A(nxt, 0);
            READ_B(nxt, 0, 2);
        }
    }

    { EMIT2(4, 8); }
}

// ---------------- launcher ----------------

extern "C" void kernel_launch(void* const* d_in, const int* in_sizes, int n_in,
                              void* d_out, int out_size, void* d_ws, size_t ws_size,
                              hipStream_t stream) {
    (void)n_in; (void)out_size;
    const float* x  = (const float*)d_in[0];
    const float* w1 = (const float*)d_in[1];
    const float* w2 = (const float*)d_in[2];
    float* out = (float*)d_out;

    const int D = 2048, H = 8192;
    const long long M = (long long)in_sizes[0] / D;  // 8192

    char* base = (char*)d_ws;
    size_t off = 0;
    auto alloc = [&](size_t bytes) -> char* {
        char* r = base + off;
        off = (off + bytes + 255) & ~(size_t)255;
        return r;
    };

    const bool fullM = ws_size >= (size_t)236 * 1024 * 1024;
    const long long MC = fullM ? M : M / 2;

    float* part = (float*)alloc(4096 * 4);
    float* scales = (float*)alloc(256);
    float* dqx = (float*)alloc((size_t)M * 4);
    float* dqh = (float*)alloc((size_t)M * 4);
    signed char* wq = (signed char*)alloc((size_t)H * D);      // w1 then w2 overlay
    signed char* xq = (signed char*)alloc((size_t)M * D);
    signed char* hq = (signed char*)alloc((size_t)M * H);      // int8 h (full)
    unsigned short* hf = (unsigned short*)alloc((size_t)MC * H * 2);  // fp16 h

    const int nw4 = H * D / 4;
    abssum2<<<4096, TPB, 0, stream>>>(w1, w2, nw4, part);
    finalize_scales<<<1, TPB, 0, stream>>>(part, scales, 1.0f / (float)(H * D));
    quant_w_i8<<<2048, TPB, 0, stream>>>(w1, wq, scales, 0, nw4);
    quant_x_i8<2><<<(int)M, TPB, 0, stream>>>(x, xq, dqx, D);

    if (fullM) {
        gemm1p<<<dim3(32, 8), 512, 0, stream>>>(xq, wq, hf, H, D, dqx, scales, 4);
        quant_h_i8<4><<<(int)M, TPB, 0, stream>>>(hf, hq, dqh, H);
    } else {
        for (int g = 0; g < 2; ++g) {
            const long long m0 = g * MC;
            gemm1p<<<dim3(32, 8), 512, 0, stream>>>(
                xq + m0 * D, wq, hf, H, D, dqx + m0, scales, 2);
            quant_h_i8<4><<<(int)MC, TPB, 0, stream>>>(hf, hq + m0 * H, dqh + m0, H);
        }
    }

    quant_w_i8<<<2048, TPB, 0, stream>>>(w2, wq, scales, 1, nw4);

    gemm2k<<<dim3(D / 256, (int)(M / 256)), 512, 0, stream>>>(
        hq, wq, out, D, H, dqh, scales);
}